// Round 11
// baseline (535.782 us; speedup 1.0000x reference)
//
#include <hip/hip_runtime.h>
#include <math.h>

#define LN_EPS 1e-5f
#define XS2 264   // padded X row stride in halves (132 dwords ≡ 4 mod 32 banks)

typedef __attribute__((ext_vector_type(8))) _Float16 f16x8;
typedef __attribute__((ext_vector_type(4))) _Float16 f16x4;
typedef __attribute__((ext_vector_type(4))) float f32x4;

__device__ __forceinline__ float sigmoidf(float x) { return 1.0f / (1.0f + expf(-x)); }
// fast silu-grade sigmoid: v_exp + v_rcp, ~1e-7 rel err (<< fp16x2 noise floor)
__device__ __forceinline__ float sigmoid_fast(float x) {
    return __builtin_amdgcn_rcpf(1.0f + __expf(-x));
}

// ---------------------------------------------------------------------------
// Fused weight prep: loc/cls/box MLP stacks + 3 lateral weights -> hi/lo fp16
// fragment-packed (frag g, plane p: f16x8 unit (g*2+p)*64+lane).
// MLP stacks: g=(l*8+ks)*16+nt, 512 groups each. Laterals: g=ks*16+nt.
// Grid 608 x 256 (2432 groups).
// ---------------------------------------------------------------------------
__global__ __launch_bounds__(256) void prep_all(
    const float* __restrict__ locW, const float* __restrict__ clsW,
    const float* __restrict__ boxW,
    const float* __restrict__ lw3, const float* __restrict__ lw4,
    const float* __restrict__ lw5,
    _Float16* __restrict__ locP, _Float16* __restrict__ clsP,
    _Float16* __restrict__ boxP,
    _Float16* __restrict__ w3, _Float16* __restrict__ w4,
    _Float16* __restrict__ w5)
{
    const int t = threadIdx.x, lane = t & 63;
    const int gi = blockIdx.x * 4 + (t >> 6);
    const float* W; _Float16* P; int g, Cin = 0; bool mlp;
    if (gi < 512)        { W = locW; P = locP; g = gi;        mlp = true; }
    else if (gi < 1024)  { W = clsW; P = clsP; g = gi - 512;  mlp = true; }
    else if (gi < 1536)  { W = boxW; P = boxP; g = gi - 1024; mlp = true; }
    else if (gi < 1664)  { W = lw3;  P = w3;   g = gi - 1536; mlp = false; Cin = 256; }
    else if (gi < 1920)  { W = lw4;  P = w4;   g = gi - 1664; mlp = false; Cin = 512; }
    else                 { W = lw5;  P = w5;   g = gi - 1920; mlp = false; Cin = 1024; }

    _Float16 h[8], m[8];
    if (mlp) {
        const int nt = g & 15, ks = (g >> 4) & 7, l = g >> 7;
        const int n = nt * 16 + (lane & 15);
        const int k0 = ks * 32 + (lane >> 4) * 8;
#pragma unroll
        for (int j = 0; j < 8; j++) {
            const float f = W[(size_t)l * 65536 + (size_t)(k0 + j) * 256 + n];
            h[j] = (_Float16)f;
            m[j] = (_Float16)(f - (float)h[j]);
        }
    } else {
        const int nt = g & 15, ks = g >> 4;
        const int n = nt * 16 + (lane & 15);
        const int k0 = ks * 32 + (lane >> 4) * 8;
#pragma unroll
        for (int j = 0; j < 8; j++) {
            const float f = W[(size_t)n * Cin + k0 + j];
            h[j] = (_Float16)f;
            m[j] = (_Float16)(f - (float)h[j]);
        }
    }
    const size_t oh = ((size_t)(g * 2 + 0) * 64 + lane) * 8;
    const size_t om = ((size_t)(g * 2 + 1) * 64 + lane) * 8;
#pragma unroll
    for (int j = 0; j < 8; j++) { P[oh + j] = h[j]; P[om + j] = m[j]; }
}

// ---------------------------------------------------------------------------
// FUSED lateral conv+BN + loc MLP. 32 px rows per block, 512 thr (8 waves).
// v4: OCCUPANCY-SHAPED REGISTER BUDGET. Mechanism (rounds 7-9): the backend
// clamps regs to the LDS-implied occupancy (36 KB -> 4 blocks/CU -> 8
// waves/SIMD -> 64-reg budget) and spills past it regardless of
// launch_bounds. Fix: pad LDS to 56.8 KB -> 2 blocks/CU -> 4 waves/SIMD ->
// 128-reg budget, then the 2-deep pipeline (4 rotating x-buffers, ~110 live
// regs) fits. 1-deep@64reg covered ~140cy of ~200cy L2 latency; 2-deep
// covers fully. Spill signal: VGPR stays 64 or WRITE_SIZE > 60 MB.
// Part B: proven 32-row loc core, coop LN stats. lv5 (CH=32) first.
// Grid B*168.
// ---------------------------------------------------------------------------
__global__ __launch_bounds__(512, 4) void lateral_loc(
    const float* __restrict__ x3, const float* __restrict__ x4,
    const float* __restrict__ x5,
    const _Float16* __restrict__ w3, const _Float16* __restrict__ w4,
    const _Float16* __restrict__ w5,
    const float* __restrict__ bng, const float* __restrict__ bnb,
    const float* __restrict__ bnm, const float* __restrict__ bnv,
    const _Float16* __restrict__ Wpk, const float* __restrict__ bs,
    const float* __restrict__ lng, const float* __restrict__ lnb,
    const float* __restrict__ Wf, const float* __restrict__ bfp,
    float* __restrict__ flat, float* __restrict__ logits, int B)
{
    __shared__ _Float16 Xh[32 * XS2];
    __shared__ _Float16 Xm[32 * XS2];
    __shared__ float red[2 * 32 * 9];   // [plane][row][wave], stride 9
    __shared__ float2 stat[32];         // (mean, rstd) per row
    __shared__ float lds_pad[5120];     // 20 KB occupancy shaping (see header)

    const int bid = blockIdx.x;
    // keep lds_pad alive; never true at our grid sizes but unprovable
    if (bid == 0x3fffffff) {
        lds_pad[threadIdx.x] = bs[threadIdx.x];
        __syncthreads();
        logits[threadIdx.x] = lds_pad[511 - threadIdx.x];
    }

    const int n5 = B * 8, n4 = B * 32;
    const float* x; const _Float16* wp; int CH, HW, base, rb, lv;
    if (bid < n5)            { x = x5; wp = w5; CH = 32; HW = 256;  base = 5120; rb = bid * 32;             lv = 2; }
    else if (bid < n5 + n4)  { x = x4; wp = w4; CH = 16; HW = 1024; base = 4096; rb = (bid - n5) * 32;      lv = 1; }
    else                     { x = x3; wp = w3; CH = 8;  HW = 4096; base = 0;    rb = (bid - n5 - n4) * 32; lv = 0; }
    const int b    = rb / HW;
    const int px0  = rb % HW;
    const int row0 = b * 5376 + base + px0;

    const int t = threadIdx.x, lane = t & 63, w = t >> 6;
    const int ar = lane & 15, quad = lane >> 4;
    const f16x8* WBP = (const f16x8*)wp;
    const f16x8* BP  = (const f16x8*)Wpk;

    f32x4 acc[2][2];
#pragma unroll
    for (int mt = 0; mt < 2; mt++)
#pragma unroll
        for (int q = 0; q < 2; q++) acc[mt][q] = (f32x4){0.f, 0.f, 0.f, 0.f};

    // ---- Part A: lateral conv, 2-deep software pipeline (macro form) ----
    {
        const float* xb = x + (size_t)b * (CH * 32) * HW;
        const float* xq = xb + (size_t)(quad * 8) * HW + px0 + ar;

        float xA[16], xB[16], xC[16], xD[16];

#define LOADX_(ks, X)                                                         \
        {                                                                     \
            const float* xp_ = xq + (size_t)((ks) * 32) * HW;                 \
            _Pragma("unroll")                                                 \
            for (int mt_ = 0; mt_ < 2; mt_++) {                               \
                _Pragma("unroll")                                             \
                for (int j_ = 0; j_ < 8; j_++)                                \
                    X[mt_ * 8 + j_] = xp_[(size_t)j_ * HW + mt_ * 16];        \
            }                                                                 \
        }

#define STEP_(ks, X)                                                          \
        {                                                                     \
            f16x8 wh_[2], wm_[2];                                             \
            _Pragma("unroll")                                                 \
            for (int q_ = 0; q_ < 2; q_++) {                                  \
                const int g_ = (ks) * 16 + (w * 2 + q_);                      \
                wh_[q_] = WBP[(g_ * 2 + 0) * 64 + lane];                      \
                wm_[q_] = WBP[(g_ * 2 + 1) * 64 + lane];                      \
            }                                                                 \
            f16x8 aH_[2], aM_[2];                                             \
            _Pragma("unroll")                                                 \
            for (int mt_ = 0; mt_ < 2; mt_++) {                               \
                _Pragma("unroll")                                             \
                for (int p_ = 0; p_ < 4; p_++) {                              \
                    const float v0_ = X[mt_ * 8 + 2 * p_];                    \
                    const float v1_ = X[mt_ * 8 + 2 * p_ + 1];                \
                    const auto h2_ = __builtin_amdgcn_cvt_pkrtz(v0_, v1_);    \
                    const auto m2_ = __builtin_amdgcn_cvt_pkrtz(               \
                        v0_ - (float)h2_[0], v1_ - (float)h2_[1]);            \
                    aH_[mt_][2 * p_]     = (_Float16)h2_[0];                  \
                    aH_[mt_][2 * p_ + 1] = (_Float16)h2_[1];                  \
                    aM_[mt_][2 * p_]     = (_Float16)m2_[0];                  \
                    aM_[mt_][2 * p_ + 1] = (_Float16)m2_[1];                  \
                }                                                             \
            }                                                                 \
            _Pragma("unroll")                                                 \
            for (int q_ = 0; q_ < 2; q_++)                                    \
                _Pragma("unroll")                                             \
                for (int mt_ = 0; mt_ < 2; mt_++)                             \
                    acc[mt_][q_] = __builtin_amdgcn_mfma_f32_16x16x32_f16(    \
                        aH_[mt_], wh_[q_], acc[mt_][q_], 0, 0, 0);            \
            _Pragma("unroll")                                                 \
            for (int q_ = 0; q_ < 2; q_++)                                    \
                _Pragma("unroll")                                             \
                for (int mt_ = 0; mt_ < 2; mt_++)                             \
                    acc[mt_][q_] = __builtin_amdgcn_mfma_f32_16x16x32_f16(    \
                        aH_[mt_], wm_[q_], acc[mt_][q_], 0, 0, 0);            \
            _Pragma("unroll")                                                 \
            for (int q_ = 0; q_ < 2; q_++)                                    \
                _Pragma("unroll")                                             \
                for (int mt_ = 0; mt_ < 2; mt_++)                             \
                    acc[mt_][q_] = __builtin_amdgcn_mfma_f32_16x16x32_f16(    \
                        aM_[mt_], wh_[q_], acc[mt_][q_], 0, 0, 0);            \
        }

        LOADX_(0, xA);
        LOADX_(1, xB);
        for (int ks = 0; ks < CH; ks += 4) {
            LOADX_(ks + 2, xC);                  // distance-2 prefetch
            STEP_(ks, xA);
            LOADX_(ks + 3, xD);
            STEP_(ks + 1, xB);
            if (ks + 4 < CH) LOADX_(ks + 4, xA);
            STEP_(ks + 2, xC);
            if (ks + 5 < CH) LOADX_(ks + 5, xB);
            STEP_(ks + 3, xD);
        }
#undef LOADX_
#undef STEP_
    }

    // BN epilogue -> flat (fp32, cached write-back) + Xh/Xm LDS split
#pragma unroll
    for (int q = 0; q < 2; q++) {
        const int col = (w * 2 + q) * 16 + ar;
        const float sc = bng[lv * 256 + col] * rsqrtf(bnv[lv * 256 + col] + LN_EPS);
        const float mh = bnm[lv * 256 + col];
        const float bb = bnb[lv * 256 + col];
#pragma unroll
        for (int mt = 0; mt < 2; mt++)
#pragma unroll
            for (int r = 0; r < 4; r++) {
                const int lr = mt * 16 + quad * 4 + r;
                const float v = (acc[mt][q][r] - mh) * sc + bb;
                flat[((size_t)row0 + lr) * 256 + col] = v;
                const _Float16 h = (_Float16)v;
                Xh[lr * XS2 + col] = h;
                Xm[lr * XS2 + col] = (_Float16)(v - (float)h);
            }
    }

    // ---- Part B: loc MLP (proven 32-row core) ----
    for (int l = 0; l < 4; l++) {
        __syncthreads();
#pragma unroll
        for (int mt = 0; mt < 2; mt++)
#pragma unroll
            for (int q = 0; q < 2; q++) acc[mt][q] = (f32x4){0.f, 0.f, 0.f, 0.f};
#pragma unroll
        for (int ks = 0; ks < 8; ks++) {
            const int ao = ks * 32 + quad * 8;
            f16x8 bh[2], bm[2];
#pragma unroll
            for (int q = 0; q < 2; q++) {
                const int g = (l * 8 + ks) * 16 + (w * 2 + q);
                bh[q] = BP[(g * 2 + 0) * 64 + lane];
                bm[q] = BP[(g * 2 + 1) * 64 + lane];
            }
            f16x8 ah[2], am[2];
#pragma unroll
            for (int mt = 0; mt < 2; mt++) {
                ah[mt] = *(const f16x8*)&Xh[(ar + mt * 16) * XS2 + ao];
                am[mt] = *(const f16x8*)&Xm[(ar + mt * 16) * XS2 + ao];
            }
#pragma unroll
            for (int q = 0; q < 2; q++)
#pragma unroll
                for (int mt = 0; mt < 2; mt++)
                    acc[mt][q] = __builtin_amdgcn_mfma_f32_16x16x32_f16(ah[mt], bh[q], acc[mt][q], 0, 0, 0);
#pragma unroll
            for (int q = 0; q < 2; q++)
#pragma unroll
                for (int mt = 0; mt < 2; mt++)
                    acc[mt][q] = __builtin_amdgcn_mfma_f32_16x16x32_f16(ah[mt], bm[q], acc[mt][q], 0, 0, 0);
#pragma unroll
            for (int q = 0; q < 2; q++)
#pragma unroll
                for (int mt = 0; mt < 2; mt++)
                    acc[mt][q] = __builtin_amdgcn_mfma_f32_16x16x32_f16(am[mt], bh[q], acc[mt][q], 0, 0, 0);
        }

        float bcol[2];
#pragma unroll
        for (int q = 0; q < 2; q++) bcol[q] = bs[l * 256 + (w * 2 + q) * 16 + ar];
#pragma unroll
        for (int mt = 0; mt < 2; mt++)
#pragma unroll
            for (int q = 0; q < 2; q++)
#pragma unroll
                for (int r = 0; r < 4; r++) acc[mt][q][r] += bcol[q];

        // phase 1: per-wave partial (sum over this wave's 32 cols)
#pragma unroll
        for (int mt = 0; mt < 2; mt++)
#pragma unroll
            for (int r = 0; r < 4; r++) {
                float s  = acc[mt][0][r] + acc[mt][1][r];
                float ss = acc[mt][0][r] * acc[mt][0][r] + acc[mt][1][r] * acc[mt][1][r];
#pragma unroll
                for (int off = 1; off < 16; off <<= 1) {
                    s  += __shfl_xor(s, off, 64);
                    ss += __shfl_xor(ss, off, 64);
                }
                if (ar == 0) {
                    const int row = mt * 16 + quad * 4 + r;
                    red[row * 9 + w] = s;
                    red[288 + row * 9 + w] = ss;
                }
            }
        __syncthreads();

        // phase 2: cooperative stats (one thread per row)
        if (t < 32) {
            float s = 0.f, ss = 0.f;
#pragma unroll
            for (int q = 0; q < 8; q++) { s += red[t * 9 + q]; ss += red[288 + t * 9 + q]; }
            const float mn = s * (1.0f / 256.0f);
            float2 sv;
            sv.x = mn;
            sv.y = rsqrtf(ss * (1.0f / 256.0f) - mn * mn + LN_EPS);
            stat[t] = sv;
        }
        __syncthreads();

        if (l < 3) {
            const int colb = w * 32;
            float gc[2], bc[2];
#pragma unroll
            for (int q = 0; q < 2; q++) {
                const int col = colb + q * 16 + ar;
                gc[q] = lng[l * 256 + col];
                bc[q] = lnb[l * 256 + col];
            }
#pragma unroll
            for (int mt = 0; mt < 2; mt++)
#pragma unroll
                for (int r = 0; r < 4; r++) {
                    const int row = mt * 16 + quad * 4 + r;
                    const float2 sv = stat[row];
#pragma unroll
                    for (int q = 0; q < 2; q++) {
                        float v = (acc[mt][q][r] - sv.x) * sv.y * gc[q] + bc[q];
                        v = v * sigmoid_fast(v);
                        const _Float16 h = (_Float16)v;
                        const int col = colb + q * 16 + ar;
                        Xh[row * XS2 + col] = h;
                        Xm[row * XS2 + col] = (_Float16)(v - (float)h);
                    }
                }
        } else {
            float gc[2], bc[2], wf[2];
#pragma unroll
            for (int q = 0; q < 2; q++) {
                const int col = w * 32 + q * 16 + ar;
                gc[q] = lng[3 * 256 + col];
                bc[q] = lnb[3 * 256 + col];
                wf[q] = Wf[col];
            }
#pragma unroll
            for (int mt = 0; mt < 2; mt++)
#pragma unroll
                for (int r = 0; r < 4; r++) {
                    const int row = mt * 16 + quad * 4 + r;
                    const float2 sv = stat[row];
                    float p = 0.f;
#pragma unroll
                    for (int q = 0; q < 2; q++) {
                        float v = (acc[mt][q][r] - sv.x) * sv.y * gc[q] + bc[q];
                        p += (v * sigmoid_fast(v)) * wf[q];
                    }
#pragma unroll
                    for (int off = 1; off < 16; off <<= 1) p += __shfl_xor(p, off, 64);
                    if (ar == 0) red[row * 9 + w] = p;
                }
            __syncthreads();
            if (t < 32) {
                float s = 0.f;
#pragma unroll
                for (int q = 0; q < 8; q++) s += red[t * 9 + q];
                logits[row0 + t] = s + bfp[0];
            }
        }
    }
}

// ---------------------------------------------------------------------------
// Top-100 per batch (sorted desc, ties -> lower index). Grid B, block 256.
// v3: 4-pass radix select (8 bits/pass) on monotonic uint keys -> exact
// rank-100 value in 4 parallel histogram passes; then one compaction pass
// + O(100x100) broadcast rank to emit sorted output.
// ---------------------------------------------------------------------------
__global__ __launch_bounds__(256) void topk_kernel(
    const float* __restrict__ logits, int* __restrict__ idx_out,
    float* __restrict__ out, int B)
{
    __shared__ unsigned int keys[5376];
    __shared__ int hist[256];
    __shared__ unsigned int selk[128];
    __shared__ int seli[128];
    __shared__ int eqi[1024];
    __shared__ int ctr[4];           // 0: cnt>Kthr slots, 1: eq count, 2: score>0.5 count
    __shared__ unsigned int bc[2];   // 0: prefix, 1: need

    const int t = threadIdx.x, b = blockIdx.x;

    // load + monotonic transform (order-preserving float -> uint)
#pragma unroll
    for (int k = 0; k < 21; k++) {
        const int i = t + k * 256;
        const unsigned int u = __float_as_uint(logits[b * 5376 + i]);
        keys[i] = (u & 0x80000000u) ? ~u : (u | 0x80000000u);
    }
    if (t == 0) { ctr[0] = 0; ctr[1] = 0; ctr[2] = 0; }

    unsigned int prefix = 0, pmask = 0;
    int need = 100;

    for (int pass = 0; pass < 4; pass++) {
        const int shift = 24 - pass * 8;
        hist[t] = 0;
        __syncthreads();
#pragma unroll
        for (int k = 0; k < 21; k++) {
            const unsigned int key = keys[t + k * 256];
            if (((key ^ prefix) & pmask) == 0)
                atomicAdd(&hist[(key >> shift) & 255], 1);
        }
        __syncthreads();
        if (t < 64) {
            const int h0 = hist[t * 4 + 0], h1 = hist[t * 4 + 1];
            const int h2 = hist[t * 4 + 2], h3 = hist[t * 4 + 3];
            const int sl = h0 + h1 + h2 + h3;
            // inclusive prefix sum across lanes
            int P = sl;
#pragma unroll
            for (int off = 1; off < 64; off <<= 1) {
                const int o = __shfl_up(P, off, 64);
                if (t >= off) P += o;
            }
            const int total = __shfl(P, 63, 64);
            const int suff = total - P + sl;          // sum over lane groups >= t
            const unsigned long long m = __ballot(suff >= need);
            const int t0 = 63 - __clzll(m);
            if (t == t0) {
                const int f1 = suff - h0;
                const int f2 = f1 - h1;
                const int f3 = f2 - h2;
                int bv, G;
                if (f3 >= need)      { bv = 3; G = f3 - h3; }
                else if (f2 >= need) { bv = 2; G = f3; }
                else if (f1 >= need) { bv = 1; G = f2; }
                else                 { bv = 0; G = f1; }
                bc[0] = prefix | ((unsigned int)(4 * t0 + bv) << shift);
                bc[1] = (unsigned int)(need - G);
            }
        }
        __syncthreads();
        prefix = bc[0];
        need = (int)bc[1];
        pmask = (pmask >> 8) | 0xFF000000u;
        __syncthreads();
    }
    const unsigned int Kthr = prefix;   // exact key of the rank-100 value
    const int needF = need;             // how many == Kthr to take (lowest idx first)

    // compaction
#pragma unroll
    for (int k = 0; k < 21; k++) {
        const int i = t + k * 256;
        const unsigned int key = keys[i];
        if (key > Kthr) {
            const int p = atomicAdd(&ctr[0], 1);
            selk[p] = key; seli[p] = i;
        } else if (key == Kthr) {
            const int p = atomicAdd(&ctr[1], 1);
            if (p < 1024) eqi[p] = i;
        }
    }
    __syncthreads();
    const int cg = ctr[0], ce = ctr[1];
    // append `needF` lowest-index equal elements
    for (int i = t; i < ce && i < 1024; i += 256) {
        const int my = eqi[i];
        int rank = 0;
        for (int j = 0; j < ce && j < 1024; j++) rank += (eqi[j] < my);
        if (rank < needF) { selk[cg + rank] = Kthr; seli[cg + rank] = my; }
    }
    __syncthreads();

    // rank the 100 selected (value desc, index asc) and emit
    if (t < 100) {
        const unsigned int myk = selk[t];
        const int myi = seli[t];
        int rank = 0;
        for (int j = 0; j < 100; j++) {
            const unsigned int kj = selk[j];
            const int ij = seli[j];
            rank += (kj > myk) || (kj == myk && ij < myi);
        }
        const unsigned int u = (myk & 0x80000000u) ? (myk & 0x7fffffffu) : ~myk;
        const float f = __uint_as_float(u);
        idx_out[b * 100 + rank] = myi;
        out[B + b * 100 + rank] = sigmoidf(f);
        if (f > 0.0f) atomicAdd(&ctr[2], 1);
    }
    __syncthreads();
    if (t == 0) out[b] = (float)ctr[2];
}

// ---------------------------------------------------------------------------
// Fused heads on the fp16x2 MFMA core (4 products for max margin):
// gather + 4x [GEMM+LN+SiLU] + finals. Grid (ceil(R/64), 2), block 512.
// v2: cooperative LN stats (loc's proven pattern; identical summation order).
// ---------------------------------------------------------------------------
__global__ __launch_bounds__(512) void heads_mlp_f16(
    const float* __restrict__ flat, const int* __restrict__ idxb,
    const _Float16* __restrict__ cWpk, const float* __restrict__ cbs,
    const float* __restrict__ cg, const float* __restrict__ cb,
    const float* __restrict__ cWf, const float* __restrict__ cbf,
    const _Float16* __restrict__ xWpk, const float* __restrict__ xbs,
    const float* __restrict__ xg, const float* __restrict__ xb_,
    const float* __restrict__ xWf, const float* __restrict__ xbf,
    const int* __restrict__ full_h, const int* __restrict__ full_w,
    float* __restrict__ out, int B, int R)
{
    __shared__ _Float16 Xh[64 * XS2];
    __shared__ _Float16 Xm[64 * XS2];
    __shared__ float red[2 * 64 * 9];
    __shared__ float2 stat[64];
    const int head = blockIdx.y;
    const _Float16* Wpk = head ? xWpk : cWpk;
    const float* bsv = head ? xbs : cbs;
    const float* gv_ = head ? xg : cg;
    const float* bv_ = head ? xb_ : cb;

    const int t = threadIdx.x, lane = t & 63, w = t >> 6;
    const int r0 = blockIdx.x * 64;
    const f16x8* BP = (const f16x8*)Wpk;

    // gather + fp16x2 split staging
#pragma unroll
    for (int i = 0; i < 8; i++) {
        const int f = i * 2048 + t * 4;
        const int row = f >> 8, col = f & 255;
        const int r = min(r0 + row, R - 1);
        const int n = idxb[r];
        const int b = r / 100;
        const f32x4 v = *(const f32x4*)&flat[((size_t)b * 5376 + n) * 256 + col];
        f16x4 h, m;
        h[0] = (_Float16)v[0]; m[0] = (_Float16)(v[0] - (float)h[0]);
        h[1] = (_Float16)v[1]; m[1] = (_Float16)(v[1] - (float)h[1]);
        h[2] = (_Float16)v[2]; m[2] = (_Float16)(v[2] - (float)h[2]);
        h[3] = (_Float16)v[3]; m[3] = (_Float16)(v[3] - (float)h[3]);
        *(f16x4*)&Xh[row * XS2 + col] = h;
        *(f16x4*)&Xm[row * XS2 + col] = m;
    }

    f32x4 acc[4][2];
    const int ar = lane & 15, quad = lane >> 4;

    for (int l = 0; l < 4; l++) {
        __syncthreads();
#pragma unroll
        for (int mt = 0; mt < 4; mt++)
#pragma unroll
            for (int q = 0; q < 2; q++) acc[mt][q] = (f32x4){0.f, 0.f, 0.f, 0.f};
#pragma unroll
        for (int ks = 0; ks < 8; ks++) {
            const int ao = ks * 32 + quad * 8;
            f16x8 bh[2], bm[2];
#pragma unroll
            for (int q = 0; q < 2; q++) {
                const int g = (l * 8 + ks) * 16 + (w * 2 + q);
                bh[q] = BP[(g * 2 + 0) * 64 + lane];
                bm[q] = BP[(g * 2 + 1) * 64 + lane];
            }
            f16x8 ah[4], am[4];
#pragma unroll
            for (int mt = 0; mt < 4; mt++) {
                ah[mt] = *(const f16x8*)&Xh[(ar + mt * 16) * XS2 + ao];
                am[mt] = *(const f16x8*)&Xm[(ar + mt * 16) * XS2 + ao];
            }
#pragma unroll
            for (int q = 0; q < 2; q++)
#pragma unroll
                for (int mt = 0; mt < 4; mt++)
                    acc[mt][q] = __builtin_amdgcn_mfma_f32_16x16x32_f16(ah[mt], bh[q], acc[mt][q], 0, 0, 0);
#pragma unroll
            for (int q = 0; q < 2; q++)
#pragma unroll
                for (int mt = 0; mt < 4; mt++)
                    acc[mt][q] = __builtin_amdgcn_mfma_f32_16x16x32_f16(ah[mt], bm[q], acc[mt][q], 0, 0, 0);
#pragma unroll
            for (int q = 0; q < 2; q++)
#pragma unroll
                for (int mt = 0; mt < 4; mt++)
                    acc[mt][q] = __builtin_amdgcn_mfma_f32_16x16x32_f16(am[mt], bh[q], acc[mt][q], 0, 0, 0);
#pragma unroll
            for (int q = 0; q < 2; q++)
#pragma unroll
                for (int mt = 0; mt < 4; mt++)
                    acc[mt][q] = __builtin_amdgcn_mfma_f32_16x16x32_f16(am[mt], bm[q], acc[mt][q], 0, 0, 0);
        }

        float bcol[2];
#pragma unroll
        for (int q = 0; q < 2; q++) bcol[q] = bsv[l * 256 + (w * 2 + q) * 16 + ar];
#pragma unroll
        for (int mt = 0; mt < 4; mt++)
#pragma unroll
            for (int q = 0; q < 2; q++)
#pragma unroll
                for (int r = 0; r < 4; r++) acc[mt][q][r] += bcol[q];

#pragma unroll
        for (int mt = 0; mt < 4; mt++)
#pragma unroll
            for (int r = 0; r < 4; r++) {
                float s  = acc[mt][0][r] + acc[mt][1][r];
                float ss = acc[mt][0][r] * acc[mt][0][r] + acc[mt][1][r] * acc[mt][1][r];
#pragma unroll
                for (int off = 1; off < 16; off <<= 1) {
                    s  += __shfl_xor(s, off, 64);
                    ss += __shfl_xor(ss, off, 64);
                }
                if (ar == 0) {
                    const int row = mt * 16 + quad * 4 + r;
                    red[row * 9 + w] = s;
                    red[576 + row * 9 + w] = ss;
                }
            }
        __syncthreads();
        if (t < 64) {
            float s = 0.f, ss = 0.f;
#pragma unroll
            for (int q = 0; q < 8; q++) { s += red[t * 9 + q]; ss += red[576 + t * 9 + q]; }
            const float mn = s * (1.0f / 256.0f);
            float2 sv;
            sv.x = mn;
            sv.y = rsqrtf(ss * (1.0f / 256.0f) - mn * mn + LN_EPS);
            stat[t] = sv;
        }
        __syncthreads();

#pragma unroll
        for (int q = 0; q < 2; q++) {
            const int col = (w * 2 + q) * 16 + ar;
            const float gc = gv_[l * 256 + col], bc = bv_[l * 256 + col];
#pragma unroll
            for (int mt = 0; mt < 4; mt++)
#pragma unroll
                for (int r = 0; r < 4; r++) {
                    const int row = mt * 16 + quad * 4 + r;
                    const float2 sv = stat[row];
                    float v = (acc[mt][q][r] - sv.x) * sv.y * gc + bc;
                    v = v * sigmoid_fast(v);
                    const _Float16 h = (_Float16)v;
                    Xh[row * XS2 + col] = h;
                    Xm[row * XS2 + col] = (_Float16)(v - (float)h);
                }
        }
    }
    __syncthreads();   // finals use cross-wave row mapping

    const int m = t >> 3, g = t & 7;
    const int r = r0 + m;
    if (head == 0) {
        const int jbase = g * 10;
        float lg[10];
#pragma unroll
        for (int jj = 0; jj < 10; jj++) lg[jj] = cbf[jbase + jj];
        for (int k = 0; k < 256; k++) {
            const float hv = (float)Xh[m * XS2 + k] + (float)Xm[m * XS2 + k];
            const float* wr = &cWf[k * 80 + jbase];
#pragma unroll
            for (int jj = 0; jj < 10; jj++) lg[jj] += hv * wr[jj];
        }
        float best = lg[0]; int bj = jbase;
#pragma unroll
        for (int jj = 1; jj < 10; jj++)
            if (lg[jj] > best) { best = lg[jj]; bj = jbase + jj; }
#pragma unroll
        for (int off = 1; off < 8; off <<= 1) {
            const float ob = __shfl_xor(best, off, 64);
            const int oj = __shfl_xor(bj, off, 64);
            if (ob > best || (ob == best && oj < bj)) { best = ob; bj = oj; }
        }
        if (g == 0 && r < R) out[B + B * 100 + r] = (float)bj;
    } else {
        float a[4] = {0.f, 0.f, 0.f, 0.f};
#pragma unroll
        for (int k4 = 0; k4 < 8; k4++) {
            const int kb = g * 32 + k4 * 4;
#pragma unroll
            for (int j = 0; j < 4; j++) {
                const float hv = (float)Xh[m * XS2 + kb + j] + (float)Xm[m * XS2 + kb + j];
                const float4 wf = *(const float4*)&xWf[(kb + j) * 4];
                a[0] += hv * wf.x; a[1] += hv * wf.y;
                a[2] += hv * wf.z; a[3] += hv * wf.w;
            }
        }
#pragma unroll
        for (int off = 1; off < 8; off <<= 1) {
            a[0] += __shfl_xor(a[0], off, 64);
            a[1] += __shfl_xor(a[1], off, 64);
            a[2] += __shfl_xor(a[2], off, 64);
            a[3] += __shfl_xor(a[3], off, 64);
        }
        if (g == 0 && r < R) {
            const float e0 = a[0] + xbf[0], e1 = a[1] + xbf[1];
            const float e2 = a[2] + xbf[2], e3 = a[3] + xbf[3];
            const int n = idxb[r];
            int base, gw, gh;
            if (n < 4096)      { base = 0;    gw = 64; gh = 64; }
            else if (n < 5120) { base = 4096; gw = 32; gh = 32; }
            else               { base = 5120; gw = 16; gh = 16; }
            const int p = n - base;
            const int py = p / gw, px = p % gw;
            const float gx = (px + 0.5f) / gw;
            const float gy = (py + 0.5f) / gh;
            const float fw = (float)full_w[0], fh = (float)full_h[0];
            const int ob = B + 2 * B * 100;
            out[ob + r * 4 + 0] = (gx - 0.5f / gw * expf(e0)) * fw;
            out[ob + r * 4 + 1] = (gy - 0.5f / gh * expf(e1)) * fh;
            out[ob + r * 4 + 2] = (gx + 0.5f / gw * expf(e2)) * fw;
            out[ob + r * 4 + 3] = (gy + 0.5f / gh * expf(e3)) * fh;
        }
    }
}

extern "C" void kernel_launch(void* const* d_in, const int* in_sizes, int n_in,
                              void* d_out, int out_size, void* d_ws, size_t ws_size,
                              hipStream_t stream)
{
    const float* x3  = (const float*)d_in[0];
    const float* x4  = (const float*)d_in[1];
    const float* x5  = (const float*)d_in[2];
    const float* lw3 = (const float*)d_in[3];
    const float* lw4 = (const float*)d_in[4];
    const float* lw5 = (const float*)d_in[5];
    const float* bng = (const float*)d_in[6];
    const float* bnb = (const float*)d_in[7];
    const float* bnm = (const float*)d_in[8];
    const float* bnv = (const float*)d_in[9];

    const float* loc_Ws  = (const float*)d_in[10];
    const float* loc_bs  = (const float*)d_in[11];
    const float* loc_lng = (const float*)d_in[12];
    const float* loc_lnb = (const float*)d_in[13];
    const float* loc_Wf  = (const float*)d_in[14];
    const float* loc_bf  = (const float*)d_in[15];

    const float* cls_Ws  = (const float*)d_in[16];
    const float* cls_bs  = (const float*)d_in[17];
    const float* cls_lng = (const float*)d_in[18];
    const float* cls_lnb = (const float*)d_in[19];
    const float* cls_Wf  = (const float*)d_in[20];
    const float* cls_bf  = (const float*)d_in[21];

    const float* box_Ws  = (const float*)d_in[22];
    const float* box_bs  = (const float*)d_in[23];
    const float* box_lng = (const float*)d_in[24];
    const float* box_lnb = (const float*)d_in[25];
    const float* box_Wf  = (const float*)d_in[26];
    const float* box_bf  = (const float*)d_in[27];

    const int* full_h = (const int*)d_in[28];
    const int* full_w = (const int*)d_in[29];

    const int B = in_sizes[0] / (256 * 64 * 64);   // 8
    const int M = B * 5376;                        // 43008
    const int R = B * 100;                         // 800

    float* ws = (float*)d_ws;
    float* flat = ws;                                  // [M*256] fp32
    float* loc  = flat + (size_t)M * 256;              // [M]
    int*   idxb = (int*)(loc + M);                     // [R] (padded 1024)
    _Float16* locP = (_Float16*)(idxb + 1024);         // 1 MB each
    _Float16* clsP = locP + 524288;
    _Float16* boxP = clsP + 524288;
    _Float16* w3   = boxP + 524288;                    // 256KB
    _Float16* w4   = w3 + 131072;                      // 512KB
    _Float16* w5   = w4 + 262144;                      // 1MB

    float* out = (float*)d_out;
    const dim3 blk(256);

    // 0) all weight prep (1 launch)
    prep_all<<<608, blk, 0, stream>>>(loc_Ws, cls_Ws, box_Ws, lw3, lw4, lw5,
                                      locP, clsP, boxP, w3, w4, w5);

    // 1) fused lateral conv+BN + loc MLP -> flat + logits (lv5 blocks first)
    lateral_loc<<<B * 168, dim3(512), 0, stream>>>(
        x3, x4, x5, w3, w4, w5, bng, bnb, bnm, bnv,
        locP, loc_bs, loc_lng, loc_lnb, loc_Wf, loc_bf,
        flat, loc, B);

    // 2) top-k (radix select)
    topk_kernel<<<B, blk, 0, stream>>>(loc, idxb, out, B);

    // 3) both heads (fp16x2 MFMA core, 4 products)
    heads_mlp_f16<<<dim3((R + 63) / 64, 2), dim3(512), 0, stream>>>(
        flat, idxb,
        clsP, cls_bs, cls_lng, cls_lnb, cls_Wf, cls_bf,
        boxP, box_bs, box_lng, box_lnb, box_Wf, box_bf,
        full_h, full_w, out, B, R);
}

// Round 12
// 454.265 us; speedup vs baseline: 1.1794x; 1.1794x over previous
//
#include <hip/hip_runtime.h>
#include <math.h>

#define LN_EPS 1e-5f
#define XS2 264   // padded X row stride in halves (132 dwords ≡ 4 mod 32 banks)

typedef __attribute__((ext_vector_type(8))) _Float16 f16x8;
typedef __attribute__((ext_vector_type(4))) _Float16 f16x4;
typedef __attribute__((ext_vector_type(4))) float f32x4;

__device__ __forceinline__ float sigmoidf(float x) { return 1.0f / (1.0f + expf(-x)); }
// fast silu-grade sigmoid: v_exp + v_rcp, ~1e-7 rel err (<< fp16x2 noise floor)
__device__ __forceinline__ float sigmoid_fast(float x) {
    return __builtin_amdgcn_rcpf(1.0f + __expf(-x));
}

// ---------------------------------------------------------------------------
// Fused weight prep: loc/cls/box MLP stacks + 3 lateral weights -> hi/lo fp16
// fragment-packed (frag g, plane p: f16x8 unit (g*2+p)*64+lane).
// MLP stacks: g=(l*8+ks)*16+nt, 512 groups each. Laterals: g=ks*16+nt.
// Grid 608 x 256 (2432 groups).
// ---------------------------------------------------------------------------
__global__ __launch_bounds__(256) void prep_all(
    const float* __restrict__ locW, const float* __restrict__ clsW,
    const float* __restrict__ boxW,
    const float* __restrict__ lw3, const float* __restrict__ lw4,
    const float* __restrict__ lw5,
    _Float16* __restrict__ locP, _Float16* __restrict__ clsP,
    _Float16* __restrict__ boxP,
    _Float16* __restrict__ w3, _Float16* __restrict__ w4,
    _Float16* __restrict__ w5)
{
    const int t = threadIdx.x, lane = t & 63;
    const int gi = blockIdx.x * 4 + (t >> 6);
    const float* W; _Float16* P; int g, Cin = 0; bool mlp;
    if (gi < 512)        { W = locW; P = locP; g = gi;        mlp = true; }
    else if (gi < 1024)  { W = clsW; P = clsP; g = gi - 512;  mlp = true; }
    else if (gi < 1536)  { W = boxW; P = boxP; g = gi - 1024; mlp = true; }
    else if (gi < 1664)  { W = lw3;  P = w3;   g = gi - 1536; mlp = false; Cin = 256; }
    else if (gi < 1920)  { W = lw4;  P = w4;   g = gi - 1664; mlp = false; Cin = 512; }
    else                 { W = lw5;  P = w5;   g = gi - 1920; mlp = false; Cin = 1024; }

    _Float16 h[8], m[8];
    if (mlp) {
        const int nt = g & 15, ks = (g >> 4) & 7, l = g >> 7;
        const int n = nt * 16 + (lane & 15);
        const int k0 = ks * 32 + (lane >> 4) * 8;
#pragma unroll
        for (int j = 0; j < 8; j++) {
            const float f = W[(size_t)l * 65536 + (size_t)(k0 + j) * 256 + n];
            h[j] = (_Float16)f;
            m[j] = (_Float16)(f - (float)h[j]);
        }
    } else {
        const int nt = g & 15, ks = g >> 4;
        const int n = nt * 16 + (lane & 15);
        const int k0 = ks * 32 + (lane >> 4) * 8;
#pragma unroll
        for (int j = 0; j < 8; j++) {
            const float f = W[(size_t)n * Cin + k0 + j];
            h[j] = (_Float16)f;
            m[j] = (_Float16)(f - (float)h[j]);
        }
    }
    const size_t oh = ((size_t)(g * 2 + 0) * 64 + lane) * 8;
    const size_t om = ((size_t)(g * 2 + 1) * 64 + lane) * 8;
#pragma unroll
    for (int j = 0; j < 8; j++) { P[oh + j] = h[j]; P[om + j] = m[j]; }
}

// ---------------------------------------------------------------------------
// FUSED lateral conv+BN + loc MLP. 32 px rows per block, 512 thr (8 waves).
// v5: (512,2) UNIFIED-BUDGET TEST. Mechanism (r7-r11): launch_bounds min-
// waves sets the unified VGPR+AGPR budget = 512/min_waves, split ~half arch
// / half AGPR-side: (512,4) -> 64 arch VGPR (r7/r9/r11 all pinned at 64,
// LDS padding irrelevant - r11 refuted that theory); (512,8) -> 32. The
// 2-deep pipeline needs ~110 arch regs -> requires (512,2) = 256 unified.
// HW still resides 16 waves/CU at <=128 VGPR, same as r7's measured ~12.
// Spill signal: VGPR stays 64 or WRITE_SIZE > 60 MB -> revert to r10 final.
// Part B: proven 32-row loc core, coop LN stats. lv5 (CH=32) first.
// Grid B*168.
// ---------------------------------------------------------------------------
__global__ __launch_bounds__(512, 2) void lateral_loc(
    const float* __restrict__ x3, const float* __restrict__ x4,
    const float* __restrict__ x5,
    const _Float16* __restrict__ w3, const _Float16* __restrict__ w4,
    const _Float16* __restrict__ w5,
    const float* __restrict__ bng, const float* __restrict__ bnb,
    const float* __restrict__ bnm, const float* __restrict__ bnv,
    const _Float16* __restrict__ Wpk, const float* __restrict__ bs,
    const float* __restrict__ lng, const float* __restrict__ lnb,
    const float* __restrict__ Wf, const float* __restrict__ bfp,
    float* __restrict__ flat, float* __restrict__ logits, int B)
{
    __shared__ _Float16 Xh[32 * XS2];
    __shared__ _Float16 Xm[32 * XS2];
    __shared__ float red[2 * 32 * 9];   // [plane][row][wave], stride 9
    __shared__ float2 stat[32];         // (mean, rstd) per row

    const int bid = blockIdx.x;
    const int n5 = B * 8, n4 = B * 32;
    const float* x; const _Float16* wp; int CH, HW, base, rb, lv;
    if (bid < n5)            { x = x5; wp = w5; CH = 32; HW = 256;  base = 5120; rb = bid * 32;             lv = 2; }
    else if (bid < n5 + n4)  { x = x4; wp = w4; CH = 16; HW = 1024; base = 4096; rb = (bid - n5) * 32;      lv = 1; }
    else                     { x = x3; wp = w3; CH = 8;  HW = 4096; base = 0;    rb = (bid - n5 - n4) * 32; lv = 0; }
    const int b    = rb / HW;
    const int px0  = rb % HW;
    const int row0 = b * 5376 + base + px0;

    const int t = threadIdx.x, lane = t & 63, w = t >> 6;
    const int ar = lane & 15, quad = lane >> 4;
    const f16x8* WBP = (const f16x8*)wp;
    const f16x8* BP  = (const f16x8*)Wpk;

    f32x4 acc[2][2];
#pragma unroll
    for (int mt = 0; mt < 2; mt++)
#pragma unroll
        for (int q = 0; q < 2; q++) acc[mt][q] = (f32x4){0.f, 0.f, 0.f, 0.f};

    // ---- Part A: lateral conv, 2-deep software pipeline (macro form) ----
    {
        const float* xb = x + (size_t)b * (CH * 32) * HW;
        const float* xq = xb + (size_t)(quad * 8) * HW + px0 + ar;

        float xA[16], xB[16], xC[16], xD[16];

#define LOADX_(ks, X)                                                         \
        {                                                                     \
            const float* xp_ = xq + (size_t)((ks) * 32) * HW;                 \
            _Pragma("unroll")                                                 \
            for (int mt_ = 0; mt_ < 2; mt_++) {                               \
                _Pragma("unroll")                                             \
                for (int j_ = 0; j_ < 8; j_++)                                \
                    X[mt_ * 8 + j_] = xp_[(size_t)j_ * HW + mt_ * 16];        \
            }                                                                 \
        }

#define STEP_(ks, X)                                                          \
        {                                                                     \
            f16x8 wh_[2], wm_[2];                                             \
            _Pragma("unroll")                                                 \
            for (int q_ = 0; q_ < 2; q_++) {                                  \
                const int g_ = (ks) * 16 + (w * 2 + q_);                      \
                wh_[q_] = WBP[(g_ * 2 + 0) * 64 + lane];                      \
                wm_[q_] = WBP[(g_ * 2 + 1) * 64 + lane];                      \
            }                                                                 \
            f16x8 aH_[2], aM_[2];                                             \
            _Pragma("unroll")                                                 \
            for (int mt_ = 0; mt_ < 2; mt_++) {                               \
                _Pragma("unroll")                                             \
                for (int p_ = 0; p_ < 4; p_++) {                              \
                    const float v0_ = X[mt_ * 8 + 2 * p_];                    \
                    const float v1_ = X[mt_ * 8 + 2 * p_ + 1];                \
                    const auto h2_ = __builtin_amdgcn_cvt_pkrtz(v0_, v1_);    \
                    const auto m2_ = __builtin_amdgcn_cvt_pkrtz(               \
                        v0_ - (float)h2_[0], v1_ - (float)h2_[1]);            \
                    aH_[mt_][2 * p_]     = (_Float16)h2_[0];                  \
                    aH_[mt_][2 * p_ + 1] = (_Float16)h2_[1];                  \
                    aM_[mt_][2 * p_]     = (_Float16)m2_[0];                  \
                    aM_[mt_][2 * p_ + 1] = (_Float16)m2_[1];                  \
                }                                                             \
            }                                                                 \
            _Pragma("unroll")                                                 \
            for (int q_ = 0; q_ < 2; q_++)                                    \
                _Pragma("unroll")                                             \
                for (int mt_ = 0; mt_ < 2; mt_++)                             \
                    acc[mt_][q_] = __builtin_amdgcn_mfma_f32_16x16x32_f16(    \
                        aH_[mt_], wh_[q_], acc[mt_][q_], 0, 0, 0);            \
            _Pragma("unroll")                                                 \
            for (int q_ = 0; q_ < 2; q_++)                                    \
                _Pragma("unroll")                                             \
                for (int mt_ = 0; mt_ < 2; mt_++)                             \
                    acc[mt_][q_] = __builtin_amdgcn_mfma_f32_16x16x32_f16(    \
                        aH_[mt_], wm_[q_], acc[mt_][q_], 0, 0, 0);            \
            _Pragma("unroll")                                                 \
            for (int q_ = 0; q_ < 2; q_++)                                    \
                _Pragma("unroll")                                             \
                for (int mt_ = 0; mt_ < 2; mt_++)                             \
                    acc[mt_][q_] = __builtin_amdgcn_mfma_f32_16x16x32_f16(    \
                        aM_[mt_], wh_[q_], acc[mt_][q_], 0, 0, 0);            \
        }

        LOADX_(0, xA);
        LOADX_(1, xB);
        for (int ks = 0; ks < CH; ks += 4) {
            LOADX_(ks + 2, xC);                  // distance-2 prefetch
            STEP_(ks, xA);
            LOADX_(ks + 3, xD);
            STEP_(ks + 1, xB);
            if (ks + 4 < CH) LOADX_(ks + 4, xA);
            STEP_(ks + 2, xC);
            if (ks + 5 < CH) LOADX_(ks + 5, xB);
            STEP_(ks + 3, xD);
        }
#undef LOADX_
#undef STEP_
    }

    // BN epilogue -> flat (fp32, cached write-back) + Xh/Xm LDS split
#pragma unroll
    for (int q = 0; q < 2; q++) {
        const int col = (w * 2 + q) * 16 + ar;
        const float sc = bng[lv * 256 + col] * rsqrtf(bnv[lv * 256 + col] + LN_EPS);
        const float mh = bnm[lv * 256 + col];
        const float bb = bnb[lv * 256 + col];
#pragma unroll
        for (int mt = 0; mt < 2; mt++)
#pragma unroll
            for (int r = 0; r < 4; r++) {
                const int lr = mt * 16 + quad * 4 + r;
                const float v = (acc[mt][q][r] - mh) * sc + bb;
                flat[((size_t)row0 + lr) * 256 + col] = v;
                const _Float16 h = (_Float16)v;
                Xh[lr * XS2 + col] = h;
                Xm[lr * XS2 + col] = (_Float16)(v - (float)h);
            }
    }

    // ---- Part B: loc MLP (proven 32-row core) ----
    for (int l = 0; l < 4; l++) {
        __syncthreads();
#pragma unroll
        for (int mt = 0; mt < 2; mt++)
#pragma unroll
            for (int q = 0; q < 2; q++) acc[mt][q] = (f32x4){0.f, 0.f, 0.f, 0.f};
#pragma unroll
        for (int ks = 0; ks < 8; ks++) {
            const int ao = ks * 32 + quad * 8;
            f16x8 bh[2], bm[2];
#pragma unroll
            for (int q = 0; q < 2; q++) {
                const int g = (l * 8 + ks) * 16 + (w * 2 + q);
                bh[q] = BP[(g * 2 + 0) * 64 + lane];
                bm[q] = BP[(g * 2 + 1) * 64 + lane];
            }
            f16x8 ah[2], am[2];
#pragma unroll
            for (int mt = 0; mt < 2; mt++) {
                ah[mt] = *(const f16x8*)&Xh[(ar + mt * 16) * XS2 + ao];
                am[mt] = *(const f16x8*)&Xm[(ar + mt * 16) * XS2 + ao];
            }
#pragma unroll
            for (int q = 0; q < 2; q++)
#pragma unroll
                for (int mt = 0; mt < 2; mt++)
                    acc[mt][q] = __builtin_amdgcn_mfma_f32_16x16x32_f16(ah[mt], bh[q], acc[mt][q], 0, 0, 0);
#pragma unroll
            for (int q = 0; q < 2; q++)
#pragma unroll
                for (int mt = 0; mt < 2; mt++)
                    acc[mt][q] = __builtin_amdgcn_mfma_f32_16x16x32_f16(ah[mt], bm[q], acc[mt][q], 0, 0, 0);
#pragma unroll
            for (int q = 0; q < 2; q++)
#pragma unroll
                for (int mt = 0; mt < 2; mt++)
                    acc[mt][q] = __builtin_amdgcn_mfma_f32_16x16x32_f16(am[mt], bh[q], acc[mt][q], 0, 0, 0);
        }

        float bcol[2];
#pragma unroll
        for (int q = 0; q < 2; q++) bcol[q] = bs[l * 256 + (w * 2 + q) * 16 + ar];
#pragma unroll
        for (int mt = 0; mt < 2; mt++)
#pragma unroll
            for (int q = 0; q < 2; q++)
#pragma unroll
                for (int r = 0; r < 4; r++) acc[mt][q][r] += bcol[q];

        // phase 1: per-wave partial (sum over this wave's 32 cols)
#pragma unroll
        for (int mt = 0; mt < 2; mt++)
#pragma unroll
            for (int r = 0; r < 4; r++) {
                float s  = acc[mt][0][r] + acc[mt][1][r];
                float ss = acc[mt][0][r] * acc[mt][0][r] + acc[mt][1][r] * acc[mt][1][r];
#pragma unroll
                for (int off = 1; off < 16; off <<= 1) {
                    s  += __shfl_xor(s, off, 64);
                    ss += __shfl_xor(ss, off, 64);
                }
                if (ar == 0) {
                    const int row = mt * 16 + quad * 4 + r;
                    red[row * 9 + w] = s;
                    red[288 + row * 9 + w] = ss;
                }
            }
        __syncthreads();

        // phase 2: cooperative stats (one thread per row)
        if (t < 32) {
            float s = 0.f, ss = 0.f;
#pragma unroll
            for (int q = 0; q < 8; q++) { s += red[t * 9 + q]; ss += red[288 + t * 9 + q]; }
            const float mn = s * (1.0f / 256.0f);
            float2 sv;
            sv.x = mn;
            sv.y = rsqrtf(ss * (1.0f / 256.0f) - mn * mn + LN_EPS);
            stat[t] = sv;
        }
        __syncthreads();

        if (l < 3) {
            const int colb = w * 32;
            float gc[2], bc[2];
#pragma unroll
            for (int q = 0; q < 2; q++) {
                const int col = colb + q * 16 + ar;
                gc[q] = lng[l * 256 + col];
                bc[q] = lnb[l * 256 + col];
            }
#pragma unroll
            for (int mt = 0; mt < 2; mt++)
#pragma unroll
                for (int r = 0; r < 4; r++) {
                    const int row = mt * 16 + quad * 4 + r;
                    const float2 sv = stat[row];
#pragma unroll
                    for (int q = 0; q < 2; q++) {
                        float v = (acc[mt][q][r] - sv.x) * sv.y * gc[q] + bc[q];
                        v = v * sigmoid_fast(v);
                        const _Float16 h = (_Float16)v;
                        const int col = colb + q * 16 + ar;
                        Xh[row * XS2 + col] = h;
                        Xm[row * XS2 + col] = (_Float16)(v - (float)h);
                    }
                }
        } else {
            float gc[2], bc[2], wf[2];
#pragma unroll
            for (int q = 0; q < 2; q++) {
                const int col = w * 32 + q * 16 + ar;
                gc[q] = lng[3 * 256 + col];
                bc[q] = lnb[3 * 256 + col];
                wf[q] = Wf[col];
            }
#pragma unroll
            for (int mt = 0; mt < 2; mt++)
#pragma unroll
                for (int r = 0; r < 4; r++) {
                    const int row = mt * 16 + quad * 4 + r;
                    const float2 sv = stat[row];
                    float p = 0.f;
#pragma unroll
                    for (int q = 0; q < 2; q++) {
                        float v = (acc[mt][q][r] - sv.x) * sv.y * gc[q] + bc[q];
                        p += (v * sigmoid_fast(v)) * wf[q];
                    }
#pragma unroll
                    for (int off = 1; off < 16; off <<= 1) p += __shfl_xor(p, off, 64);
                    if (ar == 0) red[row * 9 + w] = p;
                }
            __syncthreads();
            if (t < 32) {
                float s = 0.f;
#pragma unroll
                for (int q = 0; q < 8; q++) s += red[t * 9 + q];
                logits[row0 + t] = s + bfp[0];
            }
        }
    }
}

// ---------------------------------------------------------------------------
// Top-100 per batch (sorted desc, ties -> lower index). Grid B, block 256.
// v3: 4-pass radix select (8 bits/pass) on monotonic uint keys -> exact
// rank-100 value in 4 parallel histogram passes; then one compaction pass
// + O(100x100) broadcast rank to emit sorted output.
// ---------------------------------------------------------------------------
__global__ __launch_bounds__(256) void topk_kernel(
    const float* __restrict__ logits, int* __restrict__ idx_out,
    float* __restrict__ out, int B)
{
    __shared__ unsigned int keys[5376];
    __shared__ int hist[256];
    __shared__ unsigned int selk[128];
    __shared__ int seli[128];
    __shared__ int eqi[1024];
    __shared__ int ctr[4];           // 0: cnt>Kthr slots, 1: eq count, 2: score>0.5 count
    __shared__ unsigned int bc[2];   // 0: prefix, 1: need

    const int t = threadIdx.x, b = blockIdx.x;

    // load + monotonic transform (order-preserving float -> uint)
#pragma unroll
    for (int k = 0; k < 21; k++) {
        const int i = t + k * 256;
        const unsigned int u = __float_as_uint(logits[b * 5376 + i]);
        keys[i] = (u & 0x80000000u) ? ~u : (u | 0x80000000u);
    }
    if (t == 0) { ctr[0] = 0; ctr[1] = 0; ctr[2] = 0; }

    unsigned int prefix = 0, pmask = 0;
    int need = 100;

    for (int pass = 0; pass < 4; pass++) {
        const int shift = 24 - pass * 8;
        hist[t] = 0;
        __syncthreads();
#pragma unroll
        for (int k = 0; k < 21; k++) {
            const unsigned int key = keys[t + k * 256];
            if (((key ^ prefix) & pmask) == 0)
                atomicAdd(&hist[(key >> shift) & 255], 1);
        }
        __syncthreads();
        if (t < 64) {
            const int h0 = hist[t * 4 + 0], h1 = hist[t * 4 + 1];
            const int h2 = hist[t * 4 + 2], h3 = hist[t * 4 + 3];
            const int sl = h0 + h1 + h2 + h3;
            // inclusive prefix sum across lanes
            int P = sl;
#pragma unroll
            for (int off = 1; off < 64; off <<= 1) {
                const int o = __shfl_up(P, off, 64);
                if (t >= off) P += o;
            }
            const int total = __shfl(P, 63, 64);
            const int suff = total - P + sl;          // sum over lane groups >= t
            const unsigned long long m = __ballot(suff >= need);
            const int t0 = 63 - __clzll(m);
            if (t == t0) {
                const int f1 = suff - h0;
                const int f2 = f1 - h1;
                const int f3 = f2 - h2;
                int bv, G;
                if (f3 >= need)      { bv = 3; G = f3 - h3; }
                else if (f2 >= need) { bv = 2; G = f3; }
                else if (f1 >= need) { bv = 1; G = f2; }
                else                 { bv = 0; G = f1; }
                bc[0] = prefix | ((unsigned int)(4 * t0 + bv) << shift);
                bc[1] = (unsigned int)(need - G);
            }
        }
        __syncthreads();
        prefix = bc[0];
        need = (int)bc[1];
        pmask = (pmask >> 8) | 0xFF000000u;
        __syncthreads();
    }
    const unsigned int Kthr = prefix;   // exact key of the rank-100 value
    const int needF = need;             // how many == Kthr to take (lowest idx first)

    // compaction
#pragma unroll
    for (int k = 0; k < 21; k++) {
        const int i = t + k * 256;
        const unsigned int key = keys[i];
        if (key > Kthr) {
            const int p = atomicAdd(&ctr[0], 1);
            selk[p] = key; seli[p] = i;
        } else if (key == Kthr) {
            const int p = atomicAdd(&ctr[1], 1);
            if (p < 1024) eqi[p] = i;
        }
    }
    __syncthreads();
    const int cg = ctr[0], ce = ctr[1];
    // append `needF` lowest-index equal elements
    for (int i = t; i < ce && i < 1024; i += 256) {
        const int my = eqi[i];
        int rank = 0;
        for (int j = 0; j < ce && j < 1024; j++) rank += (eqi[j] < my);
        if (rank < needF) { selk[cg + rank] = Kthr; seli[cg + rank] = my; }
    }
    __syncthreads();

    // rank the 100 selected (value desc, index asc) and emit
    if (t < 100) {
        const unsigned int myk = selk[t];
        const int myi = seli[t];
        int rank = 0;
        for (int j = 0; j < 100; j++) {
            const unsigned int kj = selk[j];
            const int ij = seli[j];
            rank += (kj > myk) || (kj == myk && ij < myi);
        }
        const unsigned int u = (myk & 0x80000000u) ? (myk & 0x7fffffffu) : ~myk;
        const float f = __uint_as_float(u);
        idx_out[b * 100 + rank] = myi;
        out[B + b * 100 + rank] = sigmoidf(f);
        if (f > 0.0f) atomicAdd(&ctr[2], 1);
    }
    __syncthreads();
    if (t == 0) out[b] = (float)ctr[2];
}

// ---------------------------------------------------------------------------
// Fused heads on the fp16x2 MFMA core (4 products for max margin):
// gather + 4x [GEMM+LN+SiLU] + finals. Grid (ceil(R/64), 2), block 512.
// v2: cooperative LN stats (loc's proven pattern; identical summation order).
// ---------------------------------------------------------------------------
__global__ __launch_bounds__(512) void heads_mlp_f16(
    const float* __restrict__ flat, const int* __restrict__ idxb,
    const _Float16* __restrict__ cWpk, const float* __restrict__ cbs,
    const float* __restrict__ cg, const float* __restrict__ cb,
    const float* __restrict__ cWf, const float* __restrict__ cbf,
    const _Float16* __restrict__ xWpk, const float* __restrict__ xbs,
    const float* __restrict__ xg, const float* __restrict__ xb_,
    const float* __restrict__ xWf, const float* __restrict__ xbf,
    const int* __restrict__ full_h, const int* __restrict__ full_w,
    float* __restrict__ out, int B, int R)
{
    __shared__ _Float16 Xh[64 * XS2];
    __shared__ _Float16 Xm[64 * XS2];
    __shared__ float red[2 * 64 * 9];
    __shared__ float2 stat[64];
    const int head = blockIdx.y;
    const _Float16* Wpk = head ? xWpk : cWpk;
    const float* bsv = head ? xbs : cbs;
    const float* gv_ = head ? xg : cg;
    const float* bv_ = head ? xb_ : cb;

    const int t = threadIdx.x, lane = t & 63, w = t >> 6;
    const int r0 = blockIdx.x * 64;
    const f16x8* BP = (const f16x8*)Wpk;

    // gather + fp16x2 split staging
#pragma unroll
    for (int i = 0; i < 8; i++) {
        const int f = i * 2048 + t * 4;
        const int row = f >> 8, col = f & 255;
        const int r = min(r0 + row, R - 1);
        const int n = idxb[r];
        const int b = r / 100;
        const f32x4 v = *(const f32x4*)&flat[((size_t)b * 5376 + n) * 256 + col];
        f16x4 h, m;
        h[0] = (_Float16)v[0]; m[0] = (_Float16)(v[0] - (float)h[0]);
        h[1] = (_Float16)v[1]; m[1] = (_Float16)(v[1] - (float)h[1]);
        h[2] = (_Float16)v[2]; m[2] = (_Float16)(v[2] - (float)h[2]);
        h[3] = (_Float16)v[3]; m[3] = (_Float16)(v[3] - (float)h[3]);
        *(f16x4*)&Xh[row * XS2 + col] = h;
        *(f16x4*)&Xm[row * XS2 + col] = m;
    }

    f32x4 acc[4][2];
    const int ar = lane & 15, quad = lane >> 4;

    for (int l = 0; l < 4; l++) {
        __syncthreads();
#pragma unroll
        for (int mt = 0; mt < 4; mt++)
#pragma unroll
            for (int q = 0; q < 2; q++) acc[mt][q] = (f32x4){0.f, 0.f, 0.f, 0.f};
#pragma unroll
        for (int ks = 0; ks < 8; ks++) {
            const int ao = ks * 32 + quad * 8;
            f16x8 bh[2], bm[2];
#pragma unroll
            for (int q = 0; q < 2; q++) {
                const int g = (l * 8 + ks) * 16 + (w * 2 + q);
                bh[q] = BP[(g * 2 + 0) * 64 + lane];
                bm[q] = BP[(g * 2 + 1) * 64 + lane];
            }
            f16x8 ah[4], am[4];
#pragma unroll
            for (int mt = 0; mt < 4; mt++) {
                ah[mt] = *(const f16x8*)&Xh[(ar + mt * 16) * XS2 + ao];
                am[mt] = *(const f16x8*)&Xm[(ar + mt * 16) * XS2 + ao];
            }
#pragma unroll
            for (int q = 0; q < 2; q++)
#pragma unroll
                for (int mt = 0; mt < 4; mt++)
                    acc[mt][q] = __builtin_amdgcn_mfma_f32_16x16x32_f16(ah[mt], bh[q], acc[mt][q], 0, 0, 0);
#pragma unroll
            for (int q = 0; q < 2; q++)
#pragma unroll
                for (int mt = 0; mt < 4; mt++)
                    acc[mt][q] = __builtin_amdgcn_mfma_f32_16x16x32_f16(ah[mt], bm[q], acc[mt][q], 0, 0, 0);
#pragma unroll
            for (int q = 0; q < 2; q++)
#pragma unroll
                for (int mt = 0; mt < 4; mt++)
                    acc[mt][q] = __builtin_amdgcn_mfma_f32_16x16x32_f16(am[mt], bh[q], acc[mt][q], 0, 0, 0);
#pragma unroll
            for (int q = 0; q < 2; q++)
#pragma unroll
                for (int mt = 0; mt < 4; mt++)
                    acc[mt][q] = __builtin_amdgcn_mfma_f32_16x16x32_f16(am[mt], bm[q], acc[mt][q], 0, 0, 0);
        }

        float bcol[2];
#pragma unroll
        for (int q = 0; q < 2; q++) bcol[q] = bsv[l * 256 + (w * 2 + q) * 16 + ar];
#pragma unroll
        for (int mt = 0; mt < 4; mt++)
#pragma unroll
            for (int q = 0; q < 2; q++)
#pragma unroll
                for (int r = 0; r < 4; r++) acc[mt][q][r] += bcol[q];

#pragma unroll
        for (int mt = 0; mt < 4; mt++)
#pragma unroll
            for (int r = 0; r < 4; r++) {
                float s  = acc[mt][0][r] + acc[mt][1][r];
                float ss = acc[mt][0][r] * acc[mt][0][r] + acc[mt][1][r] * acc[mt][1][r];
#pragma unroll
                for (int off = 1; off < 16; off <<= 1) {
                    s  += __shfl_xor(s, off, 64);
                    ss += __shfl_xor(ss, off, 64);
                }
                if (ar == 0) {
                    const int row = mt * 16 + quad * 4 + r;
                    red[row * 9 + w] = s;
                    red[576 + row * 9 + w] = ss;
                }
            }
        __syncthreads();
        if (t < 64) {
            float s = 0.f, ss = 0.f;
#pragma unroll
            for (int q = 0; q < 8; q++) { s += red[t * 9 + q]; ss += red[576 + t * 9 + q]; }
            const float mn = s * (1.0f / 256.0f);
            float2 sv;
            sv.x = mn;
            sv.y = rsqrtf(ss * (1.0f / 256.0f) - mn * mn + LN_EPS);
            stat[t] = sv;
        }
        __syncthreads();

#pragma unroll
        for (int q = 0; q < 2; q++) {
            const int col = (w * 2 + q) * 16 + ar;
            const float gc = gv_[l * 256 + col], bc = bv_[l * 256 + col];
#pragma unroll
            for (int mt = 0; mt < 4; mt++)
#pragma unroll
                for (int r = 0; r < 4; r++) {
                    const int row = mt * 16 + quad * 4 + r;
                    const float2 sv = stat[row];
                    float v = (acc[mt][q][r] - sv.x) * sv.y * gc + bc;
                    v = v * sigmoid_fast(v);
                    const _Float16 h = (_Float16)v;
                    Xh[row * XS2 + col] = h;
                    Xm[row * XS2 + col] = (_Float16)(v - (float)h);
                }
        }
    }
    __syncthreads();   // finals use cross-wave row mapping

    const int m = t >> 3, g = t & 7;
    const int r = r0 + m;
    if (head == 0) {
        const int jbase = g * 10;
        float lg[10];
#pragma unroll
        for (int jj = 0; jj < 10; jj++) lg[jj] = cbf[jbase + jj];
        for (int k = 0; k < 256; k++) {
            const float hv = (float)Xh[m * XS2 + k] + (float)Xm[m * XS2 + k];
            const float* wr = &cWf[k * 80 + jbase];
#pragma unroll
            for (int jj = 0; jj < 10; jj++) lg[jj] += hv * wr[jj];
        }
        float best = lg[0]; int bj = jbase;
#pragma unroll
        for (int jj = 1; jj < 10; jj++)
            if (lg[jj] > best) { best = lg[jj]; bj = jbase + jj; }
#pragma unroll
        for (int off = 1; off < 8; off <<= 1) {
            const float ob = __shfl_xor(best, off, 64);
            const int oj = __shfl_xor(bj, off, 64);
            if (ob > best || (ob == best && oj < bj)) { best = ob; bj = oj; }
        }
        if (g == 0 && r < R) out[B + B * 100 + r] = (float)bj;
    } else {
        float a[4] = {0.f, 0.f, 0.f, 0.f};
#pragma unroll
        for (int k4 = 0; k4 < 8; k4++) {
            const int kb = g * 32 + k4 * 4;
#pragma unroll
            for (int j = 0; j < 4; j++) {
                const float hv = (float)Xh[m * XS2 + kb + j] + (float)Xm[m * XS2 + kb + j];
                const float4 wf = *(const float4*)&xWf[(kb + j) * 4];
                a[0] += hv * wf.x; a[1] += hv * wf.y;
                a[2] += hv * wf.z; a[3] += hv * wf.w;
            }
        }
#pragma unroll
        for (int off = 1; off < 8; off <<= 1) {
            a[0] += __shfl_xor(a[0], off, 64);
            a[1] += __shfl_xor(a[1], off, 64);
            a[2] += __shfl_xor(a[2], off, 64);
            a[3] += __shfl_xor(a[3], off, 64);
        }
        if (g == 0 && r < R) {
            const float e0 = a[0] + xbf[0], e1 = a[1] + xbf[1];
            const float e2 = a[2] + xbf[2], e3 = a[3] + xbf[3];
            const int n = idxb[r];
            int base, gw, gh;
            if (n < 4096)      { base = 0;    gw = 64; gh = 64; }
            else if (n < 5120) { base = 4096; gw = 32; gh = 32; }
            else               { base = 5120; gw = 16; gh = 16; }
            const int p = n - base;
            const int py = p / gw, px = p % gw;
            const float gx = (px + 0.5f) / gw;
            const float gy = (py + 0.5f) / gh;
            const float fw = (float)full_w[0], fh = (float)full_h[0];
            const int ob = B + 2 * B * 100;
            out[ob + r * 4 + 0] = (gx - 0.5f / gw * expf(e0)) * fw;
            out[ob + r * 4 + 1] = (gy - 0.5f / gh * expf(e1)) * fh;
            out[ob + r * 4 + 2] = (gx + 0.5f / gw * expf(e2)) * fw;
            out[ob + r * 4 + 3] = (gy + 0.5f / gh * expf(e3)) * fh;
        }
    }
}

extern "C" void kernel_launch(void* const* d_in, const int* in_sizes, int n_in,
                              void* d_out, int out_size, void* d_ws, size_t ws_size,
                              hipStream_t stream)
{
    const float* x3  = (const float*)d_in[0];
    const float* x4  = (const float*)d_in[1];
    const float* x5  = (const float*)d_in[2];
    const float* lw3 = (const float*)d_in[3];
    const float* lw4 = (const float*)d_in[4];
    const float* lw5 = (const float*)d_in[5];
    const float* bng = (const float*)d_in[6];
    const float* bnb = (const float*)d_in[7];
    const float* bnm = (const float*)d_in[8];
    const float* bnv = (const float*)d_in[9];

    const float* loc_Ws  = (const float*)d_in[10];
    const float* loc_bs  = (const float*)d_in[11];
    const float* loc_lng = (const float*)d_in[12];
    const float* loc_lnb = (const float*)d_in[13];
    const float* loc_Wf  = (const float*)d_in[14];
    const float* loc_bf  = (const float*)d_in[15];

    const float* cls_Ws  = (const float*)d_in[16];
    const float* cls_bs  = (const float*)d_in[17];
    const float* cls_lng = (const float*)d_in[18];
    const float* cls_lnb = (const float*)d_in[19];
    const float* cls_Wf  = (const float*)d_in[20];
    const float* cls_bf  = (const float*)d_in[21];

    const float* box_Ws  = (const float*)d_in[22];
    const float* box_bs  = (const float*)d_in[23];
    const float* box_lng = (const float*)d_in[24];
    const float* box_lnb = (const float*)d_in[25];
    const float* box_Wf  = (const float*)d_in[26];
    const float* box_bf  = (const float*)d_in[27];

    const int* full_h = (const int*)d_in[28];
    const int* full_w = (const int*)d_in[29];

    const int B = in_sizes[0] / (256 * 64 * 64);   // 8
    const int M = B * 5376;                        // 43008
    const int R = B * 100;                         // 800

    float* ws = (float*)d_ws;
    float* flat = ws;                                  // [M*256] fp32
    float* loc  = flat + (size_t)M * 256;              // [M]
    int*   idxb = (int*)(loc + M);                     // [R] (padded 1024)
    _Float16* locP = (_Float16*)(idxb + 1024);         // 1 MB each
    _Float16* clsP = locP + 524288;
    _Float16* boxP = clsP + 524288;
    _Float16* w3   = boxP + 524288;                    // 256KB
    _Float16* w4   = w3 + 131072;                      // 512KB
    _Float16* w5   = w4 + 262144;                      // 1MB

    float* out = (float*)d_out;
    const dim3 blk(256);

    // 0) all weight prep (1 launch)
    prep_all<<<608, blk, 0, stream>>>(loc_Ws, cls_Ws, box_Ws, lw3, lw4, lw5,
                                      locP, clsP, boxP, w3, w4, w5);

    // 1) fused lateral conv+BN + loc MLP -> flat + logits (lv5 blocks first)
    lateral_loc<<<B * 168, dim3(512), 0, stream>>>(
        x3, x4, x5, w3, w4, w5, bng, bnb, bnm, bnv,
        locP, loc_bs, loc_lng, loc_lnb, loc_Wf, loc_bf,
        flat, loc, B);

    // 2) top-k (radix select)
    topk_kernel<<<B, blk, 0, stream>>>(loc, idxb, out, B);

    // 3) both heads (fp16x2 MFMA core, 4 products)
    heads_mlp_f16<<<dim3((R + 63) / 64, 2), dim3(512), 0, stream>>>(
        flat, idxb,
        clsP, cls_bs, cls_lng, cls_lnb, cls_Wf, cls_bf,
        boxP, box_bs, box_lng, box_lnb, box_Wf, box_bf,
        full_h, full_w, out, B, R);
}

// Round 13
// 401.645 us; speedup vs baseline: 1.3340x; 1.1310x over previous
//
#include <hip/hip_runtime.h>
#include <math.h>

#define LN_EPS 1e-5f
#define XS2 264   // padded X row stride in halves (132 dwords ≡ 4 mod 32 banks)

typedef __attribute__((ext_vector_type(8))) _Float16 f16x8;
typedef __attribute__((ext_vector_type(4))) _Float16 f16x4;
typedef __attribute__((ext_vector_type(4))) float f32x4;

__device__ __forceinline__ float sigmoidf(float x) { return 1.0f / (1.0f + expf(-x)); }
// fast silu-grade sigmoid: v_exp + v_rcp, ~1e-7 rel err (<< fp16x2 noise floor)
__device__ __forceinline__ float sigmoid_fast(float x) {
    return __builtin_amdgcn_rcpf(1.0f + __expf(-x));
}

// ---------------------------------------------------------------------------
// Fused weight prep: loc/cls/box MLP stacks + 3 lateral weights -> hi/lo fp16
// fragment-packed (frag g, plane p: f16x8 unit (g*2+p)*64+lane).
// MLP stacks: g=(l*8+ks)*16+nt, 512 groups each. Laterals: g=ks*16+nt.
// Grid 608 x 256 (2432 groups).
// ---------------------------------------------------------------------------
__global__ __launch_bounds__(256) void prep_all(
    const float* __restrict__ locW, const float* __restrict__ clsW,
    const float* __restrict__ boxW,
    const float* __restrict__ lw3, const float* __restrict__ lw4,
    const float* __restrict__ lw5,
    _Float16* __restrict__ locP, _Float16* __restrict__ clsP,
    _Float16* __restrict__ boxP,
    _Float16* __restrict__ w3, _Float16* __restrict__ w4,
    _Float16* __restrict__ w5)
{
    const int t = threadIdx.x, lane = t & 63;
    const int gi = blockIdx.x * 4 + (t >> 6);
    const float* W; _Float16* P; int g, Cin = 0; bool mlp;
    if (gi < 512)        { W = locW; P = locP; g = gi;        mlp = true; }
    else if (gi < 1024)  { W = clsW; P = clsP; g = gi - 512;  mlp = true; }
    else if (gi < 1536)  { W = boxW; P = boxP; g = gi - 1024; mlp = true; }
    else if (gi < 1664)  { W = lw3;  P = w3;   g = gi - 1536; mlp = false; Cin = 256; }
    else if (gi < 1920)  { W = lw4;  P = w4;   g = gi - 1664; mlp = false; Cin = 512; }
    else                 { W = lw5;  P = w5;   g = gi - 1920; mlp = false; Cin = 1024; }

    _Float16 h[8], m[8];
    if (mlp) {
        const int nt = g & 15, ks = (g >> 4) & 7, l = g >> 7;
        const int n = nt * 16 + (lane & 15);
        const int k0 = ks * 32 + (lane >> 4) * 8;
#pragma unroll
        for (int j = 0; j < 8; j++) {
            const float f = W[(size_t)l * 65536 + (size_t)(k0 + j) * 256 + n];
            h[j] = (_Float16)f;
            m[j] = (_Float16)(f - (float)h[j]);
        }
    } else {
        const int nt = g & 15, ks = g >> 4;
        const int n = nt * 16 + (lane & 15);
        const int k0 = ks * 32 + (lane >> 4) * 8;
#pragma unroll
        for (int j = 0; j < 8; j++) {
            const float f = W[(size_t)n * Cin + k0 + j];
            h[j] = (_Float16)f;
            m[j] = (_Float16)(f - (float)h[j]);
        }
    }
    const size_t oh = ((size_t)(g * 2 + 0) * 64 + lane) * 8;
    const size_t om = ((size_t)(g * 2 + 1) * 64 + lane) * 8;
#pragma unroll
    for (int j = 0; j < 8; j++) { P[oh + j] = h[j]; P[om + j] = m[j]; }
}

// ---------------------------------------------------------------------------
// FUSED lateral conv+BN + loc MLP. 32 px rows per block, 512 thr (8 waves).
// Part A: 1-deep register pipeline (macro form; lambdas defeat SROA ->
// scratch, round 6). Part B: proven 32-row loc core, coop LN stats.
// SETTLED (rounds 7-12, bilaterally bracketed): launch_bounds min-waves sets
// the unified VGPR+AGPR budget; (512,4)/1-deep/64reg@38%occ = 157us BEATS
// (512,2)/2-deep/80reg@20%occ = 210us and every spill configuration. TLP >
// ILP for this kernel (barrier-synced Part B needs wave diversity). Do not
// revisit prefetch depth or bounds without restructuring the algorithm.
// Long lv5 blocks (CH=32) first. Grid B*168.
// ---------------------------------------------------------------------------
__global__ __launch_bounds__(512, 4) void lateral_loc(
    const float* __restrict__ x3, const float* __restrict__ x4,
    const float* __restrict__ x5,
    const _Float16* __restrict__ w3, const _Float16* __restrict__ w4,
    const _Float16* __restrict__ w5,
    const float* __restrict__ bng, const float* __restrict__ bnb,
    const float* __restrict__ bnm, const float* __restrict__ bnv,
    const _Float16* __restrict__ Wpk, const float* __restrict__ bs,
    const float* __restrict__ lng, const float* __restrict__ lnb,
    const float* __restrict__ Wf, const float* __restrict__ bfp,
    float* __restrict__ flat, float* __restrict__ logits, int B)
{
    __shared__ _Float16 Xh[32 * XS2];
    __shared__ _Float16 Xm[32 * XS2];
    __shared__ float red[2 * 32 * 9];   // [plane][row][wave], stride 9
    __shared__ float2 stat[32];         // (mean, rstd) per row

    const int bid = blockIdx.x;
    const int n5 = B * 8, n4 = B * 32;
    const float* x; const _Float16* wp; int CH, HW, base, rb, lv;
    if (bid < n5)            { x = x5; wp = w5; CH = 32; HW = 256;  base = 5120; rb = bid * 32;             lv = 2; }
    else if (bid < n5 + n4)  { x = x4; wp = w4; CH = 16; HW = 1024; base = 4096; rb = (bid - n5) * 32;      lv = 1; }
    else                     { x = x3; wp = w3; CH = 8;  HW = 4096; base = 0;    rb = (bid - n5 - n4) * 32; lv = 0; }
    const int b    = rb / HW;
    const int px0  = rb % HW;
    const int row0 = b * 5376 + base + px0;

    const int t = threadIdx.x, lane = t & 63, w = t >> 6;
    const int ar = lane & 15, quad = lane >> 4;
    const f16x8* WBP = (const f16x8*)wp;
    const f16x8* BP  = (const f16x8*)Wpk;

    f32x4 acc[2][2];
#pragma unroll
    for (int mt = 0; mt < 2; mt++)
#pragma unroll
        for (int q = 0; q < 2; q++) acc[mt][q] = (f32x4){0.f, 0.f, 0.f, 0.f};

    // ---- Part A: lateral conv, software-pipelined (macro form) ----
    {
        const float* xb = x + (size_t)b * (CH * 32) * HW;
        const float* xq = xb + (size_t)(quad * 8) * HW + px0 + ar;

        float xA[16], xB[16];

#define LOADX_(ks, X)                                                         \
        {                                                                     \
            const float* xp_ = xq + (size_t)((ks) * 32) * HW;                 \
            _Pragma("unroll")                                                 \
            for (int mt_ = 0; mt_ < 2; mt_++) {                               \
                _Pragma("unroll")                                             \
                for (int j_ = 0; j_ < 8; j_++)                                \
                    X[mt_ * 8 + j_] = xp_[(size_t)j_ * HW + mt_ * 16];        \
            }                                                                 \
        }

#define STEP_(ks, X)                                                          \
        {                                                                     \
            f16x8 wh_[2], wm_[2];                                             \
            _Pragma("unroll")                                                 \
            for (int q_ = 0; q_ < 2; q_++) {                                  \
                const int g_ = (ks) * 16 + (w * 2 + q_);                      \
                wh_[q_] = WBP[(g_ * 2 + 0) * 64 + lane];                      \
                wm_[q_] = WBP[(g_ * 2 + 1) * 64 + lane];                      \
            }                                                                 \
            f16x8 aH_[2], aM_[2];                                             \
            _Pragma("unroll")                                                 \
            for (int mt_ = 0; mt_ < 2; mt_++) {                               \
                _Pragma("unroll")                                             \
                for (int p_ = 0; p_ < 4; p_++) {                              \
                    const float v0_ = X[mt_ * 8 + 2 * p_];                    \
                    const float v1_ = X[mt_ * 8 + 2 * p_ + 1];                \
                    const auto h2_ = __builtin_amdgcn_cvt_pkrtz(v0_, v1_);    \
                    const auto m2_ = __builtin_amdgcn_cvt_pkrtz(               \
                        v0_ - (float)h2_[0], v1_ - (float)h2_[1]);            \
                    aH_[mt_][2 * p_]     = (_Float16)h2_[0];                  \
                    aH_[mt_][2 * p_ + 1] = (_Float16)h2_[1];                  \
                    aM_[mt_][2 * p_]     = (_Float16)m2_[0];                  \
                    aM_[mt_][2 * p_ + 1] = (_Float16)m2_[1];                  \
                }                                                             \
            }                                                                 \
            _Pragma("unroll")                                                 \
            for (int q_ = 0; q_ < 2; q_++)                                    \
                _Pragma("unroll")                                             \
                for (int mt_ = 0; mt_ < 2; mt_++)                             \
                    acc[mt_][q_] = __builtin_amdgcn_mfma_f32_16x16x32_f16(    \
                        aH_[mt_], wh_[q_], acc[mt_][q_], 0, 0, 0);            \
            _Pragma("unroll")                                                 \
            for (int q_ = 0; q_ < 2; q_++)                                    \
                _Pragma("unroll")                                             \
                for (int mt_ = 0; mt_ < 2; mt_++)                             \
                    acc[mt_][q_] = __builtin_amdgcn_mfma_f32_16x16x32_f16(    \
                        aH_[mt_], wm_[q_], acc[mt_][q_], 0, 0, 0);            \
            _Pragma("unroll")                                                 \
            for (int q_ = 0; q_ < 2; q_++)                                    \
                _Pragma("unroll")                                             \
                for (int mt_ = 0; mt_ < 2; mt_++)                             \
                    acc[mt_][q_] = __builtin_amdgcn_mfma_f32_16x16x32_f16(    \
                        aM_[mt_], wh_[q_], acc[mt_][q_], 0, 0, 0);            \
        }

        LOADX_(0, xA);
        for (int ks = 0; ks < CH; ks += 2) {
            LOADX_(ks + 1, xB);              // in flight over STEP(ks)
            STEP_(ks, xA);
            if (ks + 2 < CH) LOADX_(ks + 2, xA);
            STEP_(ks + 1, xB);
        }
#undef LOADX_
#undef STEP_
    }

    // BN epilogue -> flat (fp32, cached write-back) + Xh/Xm LDS split
#pragma unroll
    for (int q = 0; q < 2; q++) {
        const int col = (w * 2 + q) * 16 + ar;
        const float sc = bng[lv * 256 + col] * rsqrtf(bnv[lv * 256 + col] + LN_EPS);
        const float mh = bnm[lv * 256 + col];
        const float bb = bnb[lv * 256 + col];
#pragma unroll
        for (int mt = 0; mt < 2; mt++)
#pragma unroll
            for (int r = 0; r < 4; r++) {
                const int lr = mt * 16 + quad * 4 + r;
                const float v = (acc[mt][q][r] - mh) * sc + bb;
                flat[((size_t)row0 + lr) * 256 + col] = v;
                const _Float16 h = (_Float16)v;
                Xh[lr * XS2 + col] = h;
                Xm[lr * XS2 + col] = (_Float16)(v - (float)h);
            }
    }

    // ---- Part B: loc MLP (proven 32-row core) ----
    for (int l = 0; l < 4; l++) {
        __syncthreads();
#pragma unroll
        for (int mt = 0; mt < 2; mt++)
#pragma unroll
            for (int q = 0; q < 2; q++) acc[mt][q] = (f32x4){0.f, 0.f, 0.f, 0.f};
#pragma unroll
        for (int ks = 0; ks < 8; ks++) {
            const int ao = ks * 32 + quad * 8;
            f16x8 bh[2], bm[2];
#pragma unroll
            for (int q = 0; q < 2; q++) {
                const int g = (l * 8 + ks) * 16 + (w * 2 + q);
                bh[q] = BP[(g * 2 + 0) * 64 + lane];
                bm[q] = BP[(g * 2 + 1) * 64 + lane];
            }
            f16x8 ah[2], am[2];
#pragma unroll
            for (int mt = 0; mt < 2; mt++) {
                ah[mt] = *(const f16x8*)&Xh[(ar + mt * 16) * XS2 + ao];
                am[mt] = *(const f16x8*)&Xm[(ar + mt * 16) * XS2 + ao];
            }
#pragma unroll
            for (int q = 0; q < 2; q++)
#pragma unroll
                for (int mt = 0; mt < 2; mt++)
                    acc[mt][q] = __builtin_amdgcn_mfma_f32_16x16x32_f16(ah[mt], bh[q], acc[mt][q], 0, 0, 0);
#pragma unroll
            for (int q = 0; q < 2; q++)
#pragma unroll
                for (int mt = 0; mt < 2; mt++)
                    acc[mt][q] = __builtin_amdgcn_mfma_f32_16x16x32_f16(ah[mt], bm[q], acc[mt][q], 0, 0, 0);
#pragma unroll
            for (int q = 0; q < 2; q++)
#pragma unroll
                for (int mt = 0; mt < 2; mt++)
                    acc[mt][q] = __builtin_amdgcn_mfma_f32_16x16x32_f16(am[mt], bh[q], acc[mt][q], 0, 0, 0);
        }

        float bcol[2];
#pragma unroll
        for (int q = 0; q < 2; q++) bcol[q] = bs[l * 256 + (w * 2 + q) * 16 + ar];
#pragma unroll
        for (int mt = 0; mt < 2; mt++)
#pragma unroll
            for (int q = 0; q < 2; q++)
#pragma unroll
                for (int r = 0; r < 4; r++) acc[mt][q][r] += bcol[q];

        // phase 1: per-wave partial (sum over this wave's 32 cols)
#pragma unroll
        for (int mt = 0; mt < 2; mt++)
#pragma unroll
            for (int r = 0; r < 4; r++) {
                float s  = acc[mt][0][r] + acc[mt][1][r];
                float ss = acc[mt][0][r] * acc[mt][0][r] + acc[mt][1][r] * acc[mt][1][r];
#pragma unroll
                for (int off = 1; off < 16; off <<= 1) {
                    s  += __shfl_xor(s, off, 64);
                    ss += __shfl_xor(ss, off, 64);
                }
                if (ar == 0) {
                    const int row = mt * 16 + quad * 4 + r;
                    red[row * 9 + w] = s;
                    red[288 + row * 9 + w] = ss;
                }
            }
        __syncthreads();

        // phase 2: cooperative stats (one thread per row)
        if (t < 32) {
            float s = 0.f, ss = 0.f;
#pragma unroll
            for (int q = 0; q < 8; q++) { s += red[t * 9 + q]; ss += red[288 + t * 9 + q]; }
            const float mn = s * (1.0f / 256.0f);
            float2 sv;
            sv.x = mn;
            sv.y = rsqrtf(ss * (1.0f / 256.0f) - mn * mn + LN_EPS);
            stat[t] = sv;
        }
        __syncthreads();

        if (l < 3) {
            const int colb = w * 32;
            float gc[2], bc[2];
#pragma unroll
            for (int q = 0; q < 2; q++) {
                const int col = colb + q * 16 + ar;
                gc[q] = lng[l * 256 + col];
                bc[q] = lnb[l * 256 + col];
            }
#pragma unroll
            for (int mt = 0; mt < 2; mt++)
#pragma unroll
                for (int r = 0; r < 4; r++) {
                    const int row = mt * 16 + quad * 4 + r;
                    const float2 sv = stat[row];
#pragma unroll
                    for (int q = 0; q < 2; q++) {
                        float v = (acc[mt][q][r] - sv.x) * sv.y * gc[q] + bc[q];
                        v = v * sigmoid_fast(v);
                        const _Float16 h = (_Float16)v;
                        const int col = colb + q * 16 + ar;
                        Xh[row * XS2 + col] = h;
                        Xm[row * XS2 + col] = (_Float16)(v - (float)h);
                    }
                }
        } else {
            float gc[2], bc[2], wf[2];
#pragma unroll
            for (int q = 0; q < 2; q++) {
                const int col = w * 32 + q * 16 + ar;
                gc[q] = lng[3 * 256 + col];
                bc[q] = lnb[3 * 256 + col];
                wf[q] = Wf[col];
            }
#pragma unroll
            for (int mt = 0; mt < 2; mt++)
#pragma unroll
                for (int r = 0; r < 4; r++) {
                    const int row = mt * 16 + quad * 4 + r;
                    const float2 sv = stat[row];
                    float p = 0.f;
#pragma unroll
                    for (int q = 0; q < 2; q++) {
                        float v = (acc[mt][q][r] - sv.x) * sv.y * gc[q] + bc[q];
                        p += (v * sigmoid_fast(v)) * wf[q];
                    }
#pragma unroll
                    for (int off = 1; off < 16; off <<= 1) p += __shfl_xor(p, off, 64);
                    if (ar == 0) red[row * 9 + w] = p;
                }
            __syncthreads();
            if (t < 32) {
                float s = 0.f;
#pragma unroll
                for (int q = 0; q < 8; q++) s += red[t * 9 + q];
                logits[row0 + t] = s + bfp[0];
            }
        }
    }
}

// ---------------------------------------------------------------------------
// Top-100 per batch (sorted desc, ties -> lower index). Grid B, block 256.
// v3: 4-pass radix select (8 bits/pass) on monotonic uint keys -> exact
// rank-100 value in 4 parallel histogram passes; then one compaction pass
// + O(100x100) broadcast rank to emit sorted output.
// ---------------------------------------------------------------------------
__global__ __launch_bounds__(256) void topk_kernel(
    const float* __restrict__ logits, int* __restrict__ idx_out,
    float* __restrict__ out, int B)
{
    __shared__ unsigned int keys[5376];
    __shared__ int hist[256];
    __shared__ unsigned int selk[128];
    __shared__ int seli[128];
    __shared__ int eqi[1024];
    __shared__ int ctr[4];           // 0: cnt>Kthr slots, 1: eq count, 2: score>0.5 count
    __shared__ unsigned int bc[2];   // 0: prefix, 1: need

    const int t = threadIdx.x, b = blockIdx.x;

    // load + monotonic transform (order-preserving float -> uint)
#pragma unroll
    for (int k = 0; k < 21; k++) {
        const int i = t + k * 256;
        const unsigned int u = __float_as_uint(logits[b * 5376 + i]);
        keys[i] = (u & 0x80000000u) ? ~u : (u | 0x80000000u);
    }
    if (t == 0) { ctr[0] = 0; ctr[1] = 0; ctr[2] = 0; }

    unsigned int prefix = 0, pmask = 0;
    int need = 100;

    for (int pass = 0; pass < 4; pass++) {
        const int shift = 24 - pass * 8;
        hist[t] = 0;
        __syncthreads();
#pragma unroll
        for (int k = 0; k < 21; k++) {
            const unsigned int key = keys[t + k * 256];
            if (((key ^ prefix) & pmask) == 0)
                atomicAdd(&hist[(key >> shift) & 255], 1);
        }
        __syncthreads();
        if (t < 64) {
            const int h0 = hist[t * 4 + 0], h1 = hist[t * 4 + 1];
            const int h2 = hist[t * 4 + 2], h3 = hist[t * 4 + 3];
            const int sl = h0 + h1 + h2 + h3;
            // inclusive prefix sum across lanes
            int P = sl;
#pragma unroll
            for (int off = 1; off < 64; off <<= 1) {
                const int o = __shfl_up(P, off, 64);
                if (t >= off) P += o;
            }
            const int total = __shfl(P, 63, 64);
            const int suff = total - P + sl;          // sum over lane groups >= t
            const unsigned long long m = __ballot(suff >= need);
            const int t0 = 63 - __clzll(m);
            if (t == t0) {
                const int f1 = suff - h0;
                const int f2 = f1 - h1;
                const int f3 = f2 - h2;
                int bv, G;
                if (f3 >= need)      { bv = 3; G = f3 - h3; }
                else if (f2 >= need) { bv = 2; G = f3; }
                else if (f1 >= need) { bv = 1; G = f2; }
                else                 { bv = 0; G = f1; }
                bc[0] = prefix | ((unsigned int)(4 * t0 + bv) << shift);
                bc[1] = (unsigned int)(need - G);
            }
        }
        __syncthreads();
        prefix = bc[0];
        need = (int)bc[1];
        pmask = (pmask >> 8) | 0xFF000000u;
        __syncthreads();
    }
    const unsigned int Kthr = prefix;   // exact key of the rank-100 value
    const int needF = need;             // how many == Kthr to take (lowest idx first)

    // compaction
#pragma unroll
    for (int k = 0; k < 21; k++) {
        const int i = t + k * 256;
        const unsigned int key = keys[i];
        if (key > Kthr) {
            const int p = atomicAdd(&ctr[0], 1);
            selk[p] = key; seli[p] = i;
        } else if (key == Kthr) {
            const int p = atomicAdd(&ctr[1], 1);
            if (p < 1024) eqi[p] = i;
        }
    }
    __syncthreads();
    const int cg = ctr[0], ce = ctr[1];
    // append `needF` lowest-index equal elements
    for (int i = t; i < ce && i < 1024; i += 256) {
        const int my = eqi[i];
        int rank = 0;
        for (int j = 0; j < ce && j < 1024; j++) rank += (eqi[j] < my);
        if (rank < needF) { selk[cg + rank] = Kthr; seli[cg + rank] = my; }
    }
    __syncthreads();

    // rank the 100 selected (value desc, index asc) and emit
    if (t < 100) {
        const unsigned int myk = selk[t];
        const int myi = seli[t];
        int rank = 0;
        for (int j = 0; j < 100; j++) {
            const unsigned int kj = selk[j];
            const int ij = seli[j];
            rank += (kj > myk) || (kj == myk && ij < myi);
        }
        const unsigned int u = (myk & 0x80000000u) ? (myk & 0x7fffffffu) : ~myk;
        const float f = __uint_as_float(u);
        idx_out[b * 100 + rank] = myi;
        out[B + b * 100 + rank] = sigmoidf(f);
        if (f > 0.0f) atomicAdd(&ctr[2], 1);
    }
    __syncthreads();
    if (t == 0) out[b] = (float)ctr[2];
}

// ---------------------------------------------------------------------------
// Fused heads on the fp16x2 MFMA core (4 products for max margin):
// gather + 4x [GEMM+LN+SiLU] + finals. Grid (ceil(R/64), 2), block 512.
// v2: cooperative LN stats (loc's proven pattern; identical summation order).
// ---------------------------------------------------------------------------
__global__ __launch_bounds__(512) void heads_mlp_f16(
    const float* __restrict__ flat, const int* __restrict__ idxb,
    const _Float16* __restrict__ cWpk, const float* __restrict__ cbs,
    const float* __restrict__ cg, const float* __restrict__ cb,
    const float* __restrict__ cWf, const float* __restrict__ cbf,
    const _Float16* __restrict__ xWpk, const float* __restrict__ xbs,
    const float* __restrict__ xg, const float* __restrict__ xb_,
    const float* __restrict__ xWf, const float* __restrict__ xbf,
    const int* __restrict__ full_h, const int* __restrict__ full_w,
    float* __restrict__ out, int B, int R)
{
    __shared__ _Float16 Xh[64 * XS2];
    __shared__ _Float16 Xm[64 * XS2];
    __shared__ float red[2 * 64 * 9];
    __shared__ float2 stat[64];
    const int head = blockIdx.y;
    const _Float16* Wpk = head ? xWpk : cWpk;
    const float* bsv = head ? xbs : cbs;
    const float* gv_ = head ? xg : cg;
    const float* bv_ = head ? xb_ : cb;

    const int t = threadIdx.x, lane = t & 63, w = t >> 6;
    const int r0 = blockIdx.x * 64;
    const f16x8* BP = (const f16x8*)Wpk;

    // gather + fp16x2 split staging
#pragma unroll
    for (int i = 0; i < 8; i++) {
        const int f = i * 2048 + t * 4;
        const int row = f >> 8, col = f & 255;
        const int r = min(r0 + row, R - 1);
        const int n = idxb[r];
        const int b = r / 100;
        const f32x4 v = *(const f32x4*)&flat[((size_t)b * 5376 + n) * 256 + col];
        f16x4 h, m;
        h[0] = (_Float16)v[0]; m[0] = (_Float16)(v[0] - (float)h[0]);
        h[1] = (_Float16)v[1]; m[1] = (_Float16)(v[1] - (float)h[1]);
        h[2] = (_Float16)v[2]; m[2] = (_Float16)(v[2] - (float)h[2]);
        h[3] = (_Float16)v[3]; m[3] = (_Float16)(v[3] - (float)h[3]);
        *(f16x4*)&Xh[row * XS2 + col] = h;
        *(f16x4*)&Xm[row * XS2 + col] = m;
    }

    f32x4 acc[4][2];
    const int ar = lane & 15, quad = lane >> 4;

    for (int l = 0; l < 4; l++) {
        __syncthreads();
#pragma unroll
        for (int mt = 0; mt < 4; mt++)
#pragma unroll
            for (int q = 0; q < 2; q++) acc[mt][q] = (f32x4){0.f, 0.f, 0.f, 0.f};
#pragma unroll
        for (int ks = 0; ks < 8; ks++) {
            const int ao = ks * 32 + quad * 8;
            f16x8 bh[2], bm[2];
#pragma unroll
            for (int q = 0; q < 2; q++) {
                const int g = (l * 8 + ks) * 16 + (w * 2 + q);
                bh[q] = BP[(g * 2 + 0) * 64 + lane];
                bm[q] = BP[(g * 2 + 1) * 64 + lane];
            }
            f16x8 ah[4], am[4];
#pragma unroll
            for (int mt = 0; mt < 4; mt++) {
                ah[mt] = *(const f16x8*)&Xh[(ar + mt * 16) * XS2 + ao];
                am[mt] = *(const f16x8*)&Xm[(ar + mt * 16) * XS2 + ao];
            }
#pragma unroll
            for (int q = 0; q < 2; q++)
#pragma unroll
                for (int mt = 0; mt < 4; mt++)
                    acc[mt][q] = __builtin_amdgcn_mfma_f32_16x16x32_f16(ah[mt], bh[q], acc[mt][q], 0, 0, 0);
#pragma unroll
            for (int q = 0; q < 2; q++)
#pragma unroll
                for (int mt = 0; mt < 4; mt++)
                    acc[mt][q] = __builtin_amdgcn_mfma_f32_16x16x32_f16(ah[mt], bm[q], acc[mt][q], 0, 0, 0);
#pragma unroll
            for (int q = 0; q < 2; q++)
#pragma unroll
                for (int mt = 0; mt < 4; mt++)
                    acc[mt][q] = __builtin_amdgcn_mfma_f32_16x16x32_f16(am[mt], bh[q], acc[mt][q], 0, 0, 0);
#pragma unroll
            for (int q = 0; q < 2; q++)
#pragma unroll
                for (int mt = 0; mt < 4; mt++)
                    acc[mt][q] = __builtin_amdgcn_mfma_f32_16x16x32_f16(am[mt], bm[q], acc[mt][q], 0, 0, 0);
        }

        float bcol[2];
#pragma unroll
        for (int q = 0; q < 2; q++) bcol[q] = bsv[l * 256 + (w * 2 + q) * 16 + ar];
#pragma unroll
        for (int mt = 0; mt < 4; mt++)
#pragma unroll
            for (int q = 0; q < 2; q++)
#pragma unroll
                for (int r = 0; r < 4; r++) acc[mt][q][r] += bcol[q];

#pragma unroll
        for (int mt = 0; mt < 4; mt++)
#pragma unroll
            for (int r = 0; r < 4; r++) {
                float s  = acc[mt][0][r] + acc[mt][1][r];
                float ss = acc[mt][0][r] * acc[mt][0][r] + acc[mt][1][r] * acc[mt][1][r];
#pragma unroll
                for (int off = 1; off < 16; off <<= 1) {
                    s  += __shfl_xor(s, off, 64);
                    ss += __shfl_xor(ss, off, 64);
                }
                if (ar == 0) {
                    const int row = mt * 16 + quad * 4 + r;
                    red[row * 9 + w] = s;
                    red[576 + row * 9 + w] = ss;
                }
            }
        __syncthreads();
        if (t < 64) {
            float s = 0.f, ss = 0.f;
#pragma unroll
            for (int q = 0; q < 8; q++) { s += red[t * 9 + q]; ss += red[576 + t * 9 + q]; }
            const float mn = s * (1.0f / 256.0f);
            float2 sv;
            sv.x = mn;
            sv.y = rsqrtf(ss * (1.0f / 256.0f) - mn * mn + LN_EPS);
            stat[t] = sv;
        }
        __syncthreads();

#pragma unroll
        for (int q = 0; q < 2; q++) {
            const int col = (w * 2 + q) * 16 + ar;
            const float gc = gv_[l * 256 + col], bc = bv_[l * 256 + col];
#pragma unroll
            for (int mt = 0; mt < 4; mt++)
#pragma unroll
                for (int r = 0; r < 4; r++) {
                    const int row = mt * 16 + quad * 4 + r;
                    const float2 sv = stat[row];
                    float v = (acc[mt][q][r] - sv.x) * sv.y * gc + bc;
                    v = v * sigmoid_fast(v);
                    const _Float16 h = (_Float16)v;
                    Xh[row * XS2 + col] = h;
                    Xm[row * XS2 + col] = (_Float16)(v - (float)h);
                }
        }
    }
    __syncthreads();   // finals use cross-wave row mapping

    const int m = t >> 3, g = t & 7;
    const int r = r0 + m;
    if (head == 0) {
        const int jbase = g * 10;
        float lg[10];
#pragma unroll
        for (int jj = 0; jj < 10; jj++) lg[jj] = cbf[jbase + jj];
        for (int k = 0; k < 256; k++) {
            const float hv = (float)Xh[m * XS2 + k] + (float)Xm[m * XS2 + k];
            const float* wr = &cWf[k * 80 + jbase];
#pragma unroll
            for (int jj = 0; jj < 10; jj++) lg[jj] += hv * wr[jj];
        }
        float best = lg[0]; int bj = jbase;
#pragma unroll
        for (int jj = 1; jj < 10; jj++)
            if (lg[jj] > best) { best = lg[jj]; bj = jbase + jj; }
#pragma unroll
        for (int off = 1; off < 8; off <<= 1) {
            const float ob = __shfl_xor(best, off, 64);
            const int oj = __shfl_xor(bj, off, 64);
            if (ob > best || (ob == best && oj < bj)) { best = ob; bj = oj; }
        }
        if (g == 0 && r < R) out[B + B * 100 + r] = (float)bj;
    } else {
        float a[4] = {0.f, 0.f, 0.f, 0.f};
#pragma unroll
        for (int k4 = 0; k4 < 8; k4++) {
            const int kb = g * 32 + k4 * 4;
#pragma unroll
            for (int j = 0; j < 4; j++) {
                const float hv = (float)Xh[m * XS2 + kb + j] + (float)Xm[m * XS2 + kb + j];
                const float4 wf = *(const float4*)&xWf[(kb + j) * 4];
                a[0] += hv * wf.x; a[1] += hv * wf.y;
                a[2] += hv * wf.z; a[3] += hv * wf.w;
            }
        }
#pragma unroll
        for (int off = 1; off < 8; off <<= 1) {
            a[0] += __shfl_xor(a[0], off, 64);
            a[1] += __shfl_xor(a[1], off, 64);
            a[2] += __shfl_xor(a[2], off, 64);
            a[3] += __shfl_xor(a[3], off, 64);
        }
        if (g == 0 && r < R) {
            const float e0 = a[0] + xbf[0], e1 = a[1] + xbf[1];
            const float e2 = a[2] + xbf[2], e3 = a[3] + xbf[3];
            const int n = idxb[r];
            int base, gw, gh;
            if (n < 4096)      { base = 0;    gw = 64; gh = 64; }
            else if (n < 5120) { base = 4096; gw = 32; gh = 32; }
            else               { base = 5120; gw = 16; gh = 16; }
            const int p = n - base;
            const int py = p / gw, px = p % gw;
            const float gx = (px + 0.5f) / gw;
            const float gy = (py + 0.5f) / gh;
            const float fw = (float)full_w[0], fh = (float)full_h[0];
            const int ob = B + 2 * B * 100;
            out[ob + r * 4 + 0] = (gx - 0.5f / gw * expf(e0)) * fw;
            out[ob + r * 4 + 1] = (gy - 0.5f / gh * expf(e1)) * fh;
            out[ob + r * 4 + 2] = (gx + 0.5f / gw * expf(e2)) * fw;
            out[ob + r * 4 + 3] = (gy + 0.5f / gh * expf(e3)) * fh;
        }
    }
}

extern "C" void kernel_launch(void* const* d_in, const int* in_sizes, int n_in,
                              void* d_out, int out_size, void* d_ws, size_t ws_size,
                              hipStream_t stream)
{
    const float* x3  = (const float*)d_in[0];
    const float* x4  = (const float*)d_in[1];
    const float* x5  = (const float*)d_in[2];
    const float* lw3 = (const float*)d_in[3];
    const float* lw4 = (const float*)d_in[4];
    const float* lw5 = (const float*)d_in[5];
    const float* bng = (const float*)d_in[6];
    const float* bnb = (const float*)d_in[7];
    const float* bnm = (const float*)d_in[8];
    const float* bnv = (const float*)d_in[9];

    const float* loc_Ws  = (const float*)d_in[10];
    const float* loc_bs  = (const float*)d_in[11];
    const float* loc_lng = (const float*)d_in[12];
    const float* loc_lnb = (const float*)d_in[13];
    const float* loc_Wf  = (const float*)d_in[14];
    const float* loc_bf  = (const float*)d_in[15];

    const float* cls_Ws  = (const float*)d_in[16];
    const float* cls_bs  = (const float*)d_in[17];
    const float* cls_lng = (const float*)d_in[18];
    const float* cls_lnb = (const float*)d_in[19];
    const float* cls_Wf  = (const float*)d_in[20];
    const float* cls_bf  = (const float*)d_in[21];

    const float* box_Ws  = (const float*)d_in[22];
    const float* box_bs  = (const float*)d_in[23];
    const float* box_lng = (const float*)d_in[24];
    const float* box_lnb = (const float*)d_in[25];
    const float* box_Wf  = (const float*)d_in[26];
    const float* box_bf  = (const float*)d_in[27];

    const int* full_h = (const int*)d_in[28];
    const int* full_w = (const int*)d_in[29];

    const int B = in_sizes[0] / (256 * 64 * 64);   // 8
    const int M = B * 5376;                        // 43008
    const int R = B * 100;                         // 800

    float* ws = (float*)d_ws;
    float* flat = ws;                                  // [M*256] fp32
    float* loc  = flat + (size_t)M * 256;              // [M]
    int*   idxb = (int*)(loc + M);                     // [R] (padded 1024)
    _Float16* locP = (_Float16*)(idxb + 1024);         // 1 MB each
    _Float16* clsP = locP + 524288;
    _Float16* boxP = clsP + 524288;
    _Float16* w3   = boxP + 524288;                    // 256KB
    _Float16* w4   = w3 + 131072;                      // 512KB
    _Float16* w5   = w4 + 262144;                      // 1MB

    float* out = (float*)d_out;
    const dim3 blk(256);

    // 0) all weight prep (1 launch)
    prep_all<<<608, blk, 0, stream>>>(loc_Ws, cls_Ws, box_Ws, lw3, lw4, lw5,
                                      locP, clsP, boxP, w3, w4, w5);

    // 1) fused lateral conv+BN + loc MLP -> flat + logits (lv5 blocks first)
    lateral_loc<<<B * 168, dim3(512), 0, stream>>>(
        x3, x4, x5, w3, w4, w5, bng, bnb, bnm, bnv,
        locP, loc_bs, loc_lng, loc_lnb, loc_Wf, loc_bf,
        flat, loc, B);

    // 2) top-k (radix select)
    topk_kernel<<<B, blk, 0, stream>>>(loc, idxb, out, B);

    // 3) both heads (fp16x2 MFMA core, 4 products)
    heads_mlp_f16<<<dim3((R + 63) / 64, 2), dim3(512), 0, stream>>>(
        flat, idxb,
        clsP, cls_bs, cls_lng, cls_lnb, cls_Wf, cls_bf,
        boxP, box_bs, box_lng, box_lnb, box_Wf, box_bf,
        full_h, full_w, out, B, R);
}

// Round 14
// 353.488 us; speedup vs baseline: 1.5157x; 1.1362x over previous
//
#include <hip/hip_runtime.h>
#include <math.h>

#define LN_EPS 1e-5f
#define XS2 264   // padded X row stride in halves (132 dwords ≡ 4 mod 32 banks)

typedef __attribute__((ext_vector_type(8))) _Float16 f16x8;
typedef __attribute__((ext_vector_type(4))) _Float16 f16x4;
typedef __attribute__((ext_vector_type(4))) float f32x4;

__device__ __forceinline__ float sigmoidf(float x) { return 1.0f / (1.0f + expf(-x)); }
// fast silu-grade sigmoid: v_exp + v_rcp, ~1e-7 rel err (<< fp16x2 noise floor)
__device__ __forceinline__ float sigmoid_fast(float x) {
    return __builtin_amdgcn_rcpf(1.0f + __expf(-x));
}

// ---------------------------------------------------------------------------
// Fused weight prep: loc/cls/box MLP stacks + 3 lateral weights -> hi/lo fp16
// fragment-packed (frag g, plane p: f16x8 unit (g*2+p)*64+lane).
// MLP stacks: g=(l*8+ks)*16+nt, 512 groups each. Laterals: g=ks*16+nt.
// Grid 608 x 256 (2432 groups).
// ---------------------------------------------------------------------------
__global__ __launch_bounds__(256) void prep_all(
    const float* __restrict__ locW, const float* __restrict__ clsW,
    const float* __restrict__ boxW,
    const float* __restrict__ lw3, const float* __restrict__ lw4,
    const float* __restrict__ lw5,
    _Float16* __restrict__ locP, _Float16* __restrict__ clsP,
    _Float16* __restrict__ boxP,
    _Float16* __restrict__ w3, _Float16* __restrict__ w4,
    _Float16* __restrict__ w5)
{
    const int t = threadIdx.x, lane = t & 63;
    const int gi = blockIdx.x * 4 + (t >> 6);
    const float* W; _Float16* P; int g, Cin = 0; bool mlp;
    if (gi < 512)        { W = locW; P = locP; g = gi;        mlp = true; }
    else if (gi < 1024)  { W = clsW; P = clsP; g = gi - 512;  mlp = true; }
    else if (gi < 1536)  { W = boxW; P = boxP; g = gi - 1024; mlp = true; }
    else if (gi < 1664)  { W = lw3;  P = w3;   g = gi - 1536; mlp = false; Cin = 256; }
    else if (gi < 1920)  { W = lw4;  P = w4;   g = gi - 1664; mlp = false; Cin = 512; }
    else                 { W = lw5;  P = w5;   g = gi - 1920; mlp = false; Cin = 1024; }

    _Float16 h[8], m[8];
    if (mlp) {
        const int nt = g & 15, ks = (g >> 4) & 7, l = g >> 7;
        const int n = nt * 16 + (lane & 15);
        const int k0 = ks * 32 + (lane >> 4) * 8;
#pragma unroll
        for (int j = 0; j < 8; j++) {
            const float f = W[(size_t)l * 65536 + (size_t)(k0 + j) * 256 + n];
            h[j] = (_Float16)f;
            m[j] = (_Float16)(f - (float)h[j]);
        }
    } else {
        const int nt = g & 15, ks = g >> 4;
        const int n = nt * 16 + (lane & 15);
        const int k0 = ks * 32 + (lane >> 4) * 8;
#pragma unroll
        for (int j = 0; j < 8; j++) {
            const float f = W[(size_t)n * Cin + k0 + j];
            h[j] = (_Float16)f;
            m[j] = (_Float16)(f - (float)h[j]);
        }
    }
    const size_t oh = ((size_t)(g * 2 + 0) * 64 + lane) * 8;
    const size_t om = ((size_t)(g * 2 + 1) * 64 + lane) * 8;
#pragma unroll
    for (int j = 0; j < 8; j++) { P[oh + j] = h[j]; P[om + j] = m[j]; }
}

// ---------------------------------------------------------------------------
// FUSED lateral conv+BN + loc MLP. 32 px rows per block, 512 thr (8 waves).
// Part A: 1-deep register pipeline (macro form; lambdas defeat SROA ->
// scratch, round 6). Part B: proven 32-row loc core, coop LN stats.
// SETTLED (rounds 7-12, bilaterally bracketed): launch_bounds min-waves sets
// the unified VGPR+AGPR budget; (512,4)/1-deep/64reg@38%occ = 157us BEATS
// (512,2)/2-deep/80reg@20%occ = 210us and every spill configuration. TLP >
// ILP for this kernel (barrier-synced Part B needs wave diversity). Do not
// revisit prefetch depth or bounds without restructuring the algorithm.
// Long lv5 blocks (CH=32) first. Grid B*168.
// ---------------------------------------------------------------------------
__global__ __launch_bounds__(512, 4) void lateral_loc(
    const float* __restrict__ x3, const float* __restrict__ x4,
    const float* __restrict__ x5,
    const _Float16* __restrict__ w3, const _Float16* __restrict__ w4,
    const _Float16* __restrict__ w5,
    const float* __restrict__ bng, const float* __restrict__ bnb,
    const float* __restrict__ bnm, const float* __restrict__ bnv,
    const _Float16* __restrict__ Wpk, const float* __restrict__ bs,
    const float* __restrict__ lng, const float* __restrict__ lnb,
    const float* __restrict__ Wf, const float* __restrict__ bfp,
    float* __restrict__ flat, float* __restrict__ logits, int B)
{
    __shared__ _Float16 Xh[32 * XS2];
    __shared__ _Float16 Xm[32 * XS2];
    __shared__ float red[2 * 32 * 9];   // [plane][row][wave], stride 9
    __shared__ float2 stat[32];         // (mean, rstd) per row

    const int bid = blockIdx.x;
    const int n5 = B * 8, n4 = B * 32;
    const float* x; const _Float16* wp; int CH, HW, base, rb, lv;
    if (bid < n5)            { x = x5; wp = w5; CH = 32; HW = 256;  base = 5120; rb = bid * 32;             lv = 2; }
    else if (bid < n5 + n4)  { x = x4; wp = w4; CH = 16; HW = 1024; base = 4096; rb = (bid - n5) * 32;      lv = 1; }
    else                     { x = x3; wp = w3; CH = 8;  HW = 4096; base = 0;    rb = (bid - n5 - n4) * 32; lv = 0; }
    const int b    = rb / HW;
    const int px0  = rb % HW;
    const int row0 = b * 5376 + base + px0;

    const int t = threadIdx.x, lane = t & 63, w = t >> 6;
    const int ar = lane & 15, quad = lane >> 4;
    const f16x8* WBP = (const f16x8*)wp;
    const f16x8* BP  = (const f16x8*)Wpk;

    f32x4 acc[2][2];
#pragma unroll
    for (int mt = 0; mt < 2; mt++)
#pragma unroll
        for (int q = 0; q < 2; q++) acc[mt][q] = (f32x4){0.f, 0.f, 0.f, 0.f};

    // ---- Part A: lateral conv, software-pipelined (macro form) ----
    {
        const float* xb = x + (size_t)b * (CH * 32) * HW;
        const float* xq = xb + (size_t)(quad * 8) * HW + px0 + ar;

        float xA[16], xB[16];

#define LOADX_(ks, X)                                                         \
        {                                                                     \
            const float* xp_ = xq + (size_t)((ks) * 32) * HW;                 \
            _Pragma("unroll")                                                 \
            for (int mt_ = 0; mt_ < 2; mt_++) {                               \
                _Pragma("unroll")                                             \
                for (int j_ = 0; j_ < 8; j_++)                                \
                    X[mt_ * 8 + j_] = xp_[(size_t)j_ * HW + mt_ * 16];        \
            }                                                                 \
        }

#define STEP_(ks, X)                                                          \
        {                                                                     \
            f16x8 wh_[2], wm_[2];                                             \
            _Pragma("unroll")                                                 \
            for (int q_ = 0; q_ < 2; q_++) {                                  \
                const int g_ = (ks) * 16 + (w * 2 + q_);                      \
                wh_[q_] = WBP[(g_ * 2 + 0) * 64 + lane];                      \
                wm_[q_] = WBP[(g_ * 2 + 1) * 64 + lane];                      \
            }                                                                 \
            f16x8 aH_[2], aM_[2];                                             \
            _Pragma("unroll")                                                 \
            for (int mt_ = 0; mt_ < 2; mt_++) {                               \
                _Pragma("unroll")                                             \
                for (int p_ = 0; p_ < 4; p_++) {                              \
                    const float v0_ = X[mt_ * 8 + 2 * p_];                    \
                    const float v1_ = X[mt_ * 8 + 2 * p_ + 1];                \
                    const auto h2_ = __builtin_amdgcn_cvt_pkrtz(v0_, v1_);    \
                    const auto m2_ = __builtin_amdgcn_cvt_pkrtz(               \
                        v0_ - (float)h2_[0], v1_ - (float)h2_[1]);            \
                    aH_[mt_][2 * p_]     = (_Float16)h2_[0];                  \
                    aH_[mt_][2 * p_ + 1] = (_Float16)h2_[1];                  \
                    aM_[mt_][2 * p_]     = (_Float16)m2_[0];                  \
                    aM_[mt_][2 * p_ + 1] = (_Float16)m2_[1];                  \
                }                                                             \
            }                                                                 \
            _Pragma("unroll")                                                 \
            for (int q_ = 0; q_ < 2; q_++)                                    \
                _Pragma("unroll")                                             \
                for (int mt_ = 0; mt_ < 2; mt_++)                             \
                    acc[mt_][q_] = __builtin_amdgcn_mfma_f32_16x16x32_f16(    \
                        aH_[mt_], wh_[q_], acc[mt_][q_], 0, 0, 0);            \
            _Pragma("unroll")                                                 \
            for (int q_ = 0; q_ < 2; q_++)                                    \
                _Pragma("unroll")                                             \
                for (int mt_ = 0; mt_ < 2; mt_++)                             \
                    acc[mt_][q_] = __builtin_amdgcn_mfma_f32_16x16x32_f16(    \
                        aH_[mt_], wm_[q_], acc[mt_][q_], 0, 0, 0);            \
            _Pragma("unroll")                                                 \
            for (int q_ = 0; q_ < 2; q_++)                                    \
                _Pragma("unroll")                                             \
                for (int mt_ = 0; mt_ < 2; mt_++)                             \
                    acc[mt_][q_] = __builtin_amdgcn_mfma_f32_16x16x32_f16(    \
                        aM_[mt_], wh_[q_], acc[mt_][q_], 0, 0, 0);            \
        }

        LOADX_(0, xA);
        for (int ks = 0; ks < CH; ks += 2) {
            LOADX_(ks + 1, xB);              // in flight over STEP(ks)
            STEP_(ks, xA);
            if (ks + 2 < CH) LOADX_(ks + 2, xA);
            STEP_(ks + 1, xB);
        }
#undef LOADX_
#undef STEP_
    }

    // BN epilogue -> flat (fp32, cached write-back) + Xh/Xm LDS split
#pragma unroll
    for (int q = 0; q < 2; q++) {
        const int col = (w * 2 + q) * 16 + ar;
        const float sc = bng[lv * 256 + col] * rsqrtf(bnv[lv * 256 + col] + LN_EPS);
        const float mh = bnm[lv * 256 + col];
        const float bb = bnb[lv * 256 + col];
#pragma unroll
        for (int mt = 0; mt < 2; mt++)
#pragma unroll
            for (int r = 0; r < 4; r++) {
                const int lr = mt * 16 + quad * 4 + r;
                const float v = (acc[mt][q][r] - mh) * sc + bb;
                flat[((size_t)row0 + lr) * 256 + col] = v;
                const _Float16 h = (_Float16)v;
                Xh[lr * XS2 + col] = h;
                Xm[lr * XS2 + col] = (_Float16)(v - (float)h);
            }
    }

    // ---- Part B: loc MLP (proven 32-row core) ----
    for (int l = 0; l < 4; l++) {
        __syncthreads();
#pragma unroll
        for (int mt = 0; mt < 2; mt++)
#pragma unroll
            for (int q = 0; q < 2; q++) acc[mt][q] = (f32x4){0.f, 0.f, 0.f, 0.f};
#pragma unroll
        for (int ks = 0; ks < 8; ks++) {
            const int ao = ks * 32 + quad * 8;
            f16x8 bh[2], bm[2];
#pragma unroll
            for (int q = 0; q < 2; q++) {
                const int g = (l * 8 + ks) * 16 + (w * 2 + q);
                bh[q] = BP[(g * 2 + 0) * 64 + lane];
                bm[q] = BP[(g * 2 + 1) * 64 + lane];
            }
            f16x8 ah[2], am[2];
#pragma unroll
            for (int mt = 0; mt < 2; mt++) {
                ah[mt] = *(const f16x8*)&Xh[(ar + mt * 16) * XS2 + ao];
                am[mt] = *(const f16x8*)&Xm[(ar + mt * 16) * XS2 + ao];
            }
#pragma unroll
            for (int q = 0; q < 2; q++)
#pragma unroll
                for (int mt = 0; mt < 2; mt++)
                    acc[mt][q] = __builtin_amdgcn_mfma_f32_16x16x32_f16(ah[mt], bh[q], acc[mt][q], 0, 0, 0);
#pragma unroll
            for (int q = 0; q < 2; q++)
#pragma unroll
                for (int mt = 0; mt < 2; mt++)
                    acc[mt][q] = __builtin_amdgcn_mfma_f32_16x16x32_f16(ah[mt], bm[q], acc[mt][q], 0, 0, 0);
#pragma unroll
            for (int q = 0; q < 2; q++)
#pragma unroll
                for (int mt = 0; mt < 2; mt++)
                    acc[mt][q] = __builtin_amdgcn_mfma_f32_16x16x32_f16(am[mt], bh[q], acc[mt][q], 0, 0, 0);
        }

        float bcol[2];
#pragma unroll
        for (int q = 0; q < 2; q++) bcol[q] = bs[l * 256 + (w * 2 + q) * 16 + ar];
#pragma unroll
        for (int mt = 0; mt < 2; mt++)
#pragma unroll
            for (int q = 0; q < 2; q++)
#pragma unroll
                for (int r = 0; r < 4; r++) acc[mt][q][r] += bcol[q];

        // phase 1: per-wave partial (sum over this wave's 32 cols)
#pragma unroll
        for (int mt = 0; mt < 2; mt++)
#pragma unroll
            for (int r = 0; r < 4; r++) {
                float s  = acc[mt][0][r] + acc[mt][1][r];
                float ss = acc[mt][0][r] * acc[mt][0][r] + acc[mt][1][r] * acc[mt][1][r];
#pragma unroll
                for (int off = 1; off < 16; off <<= 1) {
                    s  += __shfl_xor(s, off, 64);
                    ss += __shfl_xor(ss, off, 64);
                }
                if (ar == 0) {
                    const int row = mt * 16 + quad * 4 + r;
                    red[row * 9 + w] = s;
                    red[288 + row * 9 + w] = ss;
                }
            }
        __syncthreads();

        // phase 2: cooperative stats (one thread per row)
        if (t < 32) {
            float s = 0.f, ss = 0.f;
#pragma unroll
            for (int q = 0; q < 8; q++) { s += red[t * 9 + q]; ss += red[288 + t * 9 + q]; }
            const float mn = s * (1.0f / 256.0f);
            float2 sv;
            sv.x = mn;
            sv.y = rsqrtf(ss * (1.0f / 256.0f) - mn * mn + LN_EPS);
            stat[t] = sv;
        }
        __syncthreads();

        if (l < 3) {
            const int colb = w * 32;
            float gc[2], bc[2];
#pragma unroll
            for (int q = 0; q < 2; q++) {
                const int col = colb + q * 16 + ar;
                gc[q] = lng[l * 256 + col];
                bc[q] = lnb[l * 256 + col];
            }
#pragma unroll
            for (int mt = 0; mt < 2; mt++)
#pragma unroll
                for (int r = 0; r < 4; r++) {
                    const int row = mt * 16 + quad * 4 + r;
                    const float2 sv = stat[row];
#pragma unroll
                    for (int q = 0; q < 2; q++) {
                        float v = (acc[mt][q][r] - sv.x) * sv.y * gc[q] + bc[q];
                        v = v * sigmoid_fast(v);
                        const _Float16 h = (_Float16)v;
                        const int col = colb + q * 16 + ar;
                        Xh[row * XS2 + col] = h;
                        Xm[row * XS2 + col] = (_Float16)(v - (float)h);
                    }
                }
        } else {
            float gc[2], bc[2], wf[2];
#pragma unroll
            for (int q = 0; q < 2; q++) {
                const int col = w * 32 + q * 16 + ar;
                gc[q] = lng[3 * 256 + col];
                bc[q] = lnb[3 * 256 + col];
                wf[q] = Wf[col];
            }
#pragma unroll
            for (int mt = 0; mt < 2; mt++)
#pragma unroll
                for (int r = 0; r < 4; r++) {
                    const int row = mt * 16 + quad * 4 + r;
                    const float2 sv = stat[row];
                    float p = 0.f;
#pragma unroll
                    for (int q = 0; q < 2; q++) {
                        float v = (acc[mt][q][r] - sv.x) * sv.y * gc[q] + bc[q];
                        p += (v * sigmoid_fast(v)) * wf[q];
                    }
#pragma unroll
                    for (int off = 1; off < 16; off <<= 1) p += __shfl_xor(p, off, 64);
                    if (ar == 0) red[row * 9 + w] = p;
                }
            __syncthreads();
            if (t < 32) {
                float s = 0.f;
#pragma unroll
                for (int q = 0; q < 8; q++) s += red[t * 9 + q];
                logits[row0 + t] = s + bfp[0];
            }
        }
    }
}

// ---------------------------------------------------------------------------
// Top-100 per batch (sorted desc, ties -> lower index). Grid B, block 256.
// v3: 4-pass radix select (8 bits/pass) on monotonic uint keys -> exact
// rank-100 value in 4 parallel histogram passes; then one compaction pass
// + O(100x100) broadcast rank to emit sorted output.
// ---------------------------------------------------------------------------
__global__ __launch_bounds__(256) void topk_kernel(
    const float* __restrict__ logits, int* __restrict__ idx_out,
    float* __restrict__ out, int B)
{
    __shared__ unsigned int keys[5376];
    __shared__ int hist[256];
    __shared__ unsigned int selk[128];
    __shared__ int seli[128];
    __shared__ int eqi[1024];
    __shared__ int ctr[4];           // 0: cnt>Kthr slots, 1: eq count, 2: score>0.5 count
    __shared__ unsigned int bc[2];   // 0: prefix, 1: need

    const int t = threadIdx.x, b = blockIdx.x;

    // load + monotonic transform (order-preserving float -> uint)
#pragma unroll
    for (int k = 0; k < 21; k++) {
        const int i = t + k * 256;
        const unsigned int u = __float_as_uint(logits[b * 5376 + i]);
        keys[i] = (u & 0x80000000u) ? ~u : (u | 0x80000000u);
    }
    if (t == 0) { ctr[0] = 0; ctr[1] = 0; ctr[2] = 0; }

    unsigned int prefix = 0, pmask = 0;
    int need = 100;

    for (int pass = 0; pass < 4; pass++) {
        const int shift = 24 - pass * 8;
        hist[t] = 0;
        __syncthreads();
#pragma unroll
        for (int k = 0; k < 21; k++) {
            const unsigned int key = keys[t + k * 256];
            if (((key ^ prefix) & pmask) == 0)
                atomicAdd(&hist[(key >> shift) & 255], 1);
        }
        __syncthreads();
        if (t < 64) {
            const int h0 = hist[t * 4 + 0], h1 = hist[t * 4 + 1];
            const int h2 = hist[t * 4 + 2], h3 = hist[t * 4 + 3];
            const int sl = h0 + h1 + h2 + h3;
            // inclusive prefix sum across lanes
            int P = sl;
#pragma unroll
            for (int off = 1; off < 64; off <<= 1) {
                const int o = __shfl_up(P, off, 64);
                if (t >= off) P += o;
            }
            const int total = __shfl(P, 63, 64);
            const int suff = total - P + sl;          // sum over lane groups >= t
            const unsigned long long m = __ballot(suff >= need);
            const int t0 = 63 - __clzll(m);
            if (t == t0) {
                const int f1 = suff - h0;
                const int f2 = f1 - h1;
                const int f3 = f2 - h2;
                int bv, G;
                if (f3 >= need)      { bv = 3; G = f3 - h3; }
                else if (f2 >= need) { bv = 2; G = f3; }
                else if (f1 >= need) { bv = 1; G = f2; }
                else                 { bv = 0; G = f1; }
                bc[0] = prefix | ((unsigned int)(4 * t0 + bv) << shift);
                bc[1] = (unsigned int)(need - G);
            }
        }
        __syncthreads();
        prefix = bc[0];
        need = (int)bc[1];
        pmask = (pmask >> 8) | 0xFF000000u;
        __syncthreads();
    }
    const unsigned int Kthr = prefix;   // exact key of the rank-100 value
    const int needF = need;             // how many == Kthr to take (lowest idx first)

    // compaction
#pragma unroll
    for (int k = 0; k < 21; k++) {
        const int i = t + k * 256;
        const unsigned int key = keys[i];
        if (key > Kthr) {
            const int p = atomicAdd(&ctr[0], 1);
            selk[p] = key; seli[p] = i;
        } else if (key == Kthr) {
            const int p = atomicAdd(&ctr[1], 1);
            if (p < 1024) eqi[p] = i;
        }
    }
    __syncthreads();
    const int cg = ctr[0], ce = ctr[1];
    // append `needF` lowest-index equal elements
    for (int i = t; i < ce && i < 1024; i += 256) {
        const int my = eqi[i];
        int rank = 0;
        for (int j = 0; j < ce && j < 1024; j++) rank += (eqi[j] < my);
        if (rank < needF) { selk[cg + rank] = Kthr; seli[cg + rank] = my; }
    }
    __syncthreads();

    // rank the 100 selected (value desc, index asc) and emit
    if (t < 100) {
        const unsigned int myk = selk[t];
        const int myi = seli[t];
        int rank = 0;
        for (int j = 0; j < 100; j++) {
            const unsigned int kj = selk[j];
            const int ij = seli[j];
            rank += (kj > myk) || (kj == myk && ij < myi);
        }
        const unsigned int u = (myk & 0x80000000u) ? (myk & 0x7fffffffu) : ~myk;
        const float f = __uint_as_float(u);
        idx_out[b * 100 + rank] = myi;
        out[B + b * 100 + rank] = sigmoidf(f);
        if (f > 0.0f) atomicAdd(&ctr[2], 1);
    }
    __syncthreads();
    if (t == 0) out[b] = (float)ctr[2];
}

// ---------------------------------------------------------------------------
// Fused heads on the fp16x2 MFMA core (4 products for max margin):
// gather + 4x [GEMM+LN+SiLU] + finals.
// v3: 32-row blocks -> grid (R/32=25, 2) = 50 blocks (was (13,2)=26: only
// 26 of 256 CUs busy, latency-bound). Same loc-core geometry (acc[2][2],
// coop LN stats); finals use 8 thr/row over 32 rows (t<256). LDS 71->36 KB.
// ---------------------------------------------------------------------------
__global__ __launch_bounds__(512) void heads_mlp_f16(
    const float* __restrict__ flat, const int* __restrict__ idxb,
    const _Float16* __restrict__ cWpk, const float* __restrict__ cbs,
    const float* __restrict__ cg, const float* __restrict__ cb,
    const float* __restrict__ cWf, const float* __restrict__ cbf,
    const _Float16* __restrict__ xWpk, const float* __restrict__ xbs,
    const float* __restrict__ xg, const float* __restrict__ xb_,
    const float* __restrict__ xWf, const float* __restrict__ xbf,
    const int* __restrict__ full_h, const int* __restrict__ full_w,
    float* __restrict__ out, int B, int R)
{
    __shared__ _Float16 Xh[32 * XS2];
    __shared__ _Float16 Xm[32 * XS2];
    __shared__ float red[2 * 32 * 9];
    __shared__ float2 stat[32];
    const int head = blockIdx.y;
    const _Float16* Wpk = head ? xWpk : cWpk;
    const float* bsv = head ? xbs : cbs;
    const float* gv_ = head ? xg : cg;
    const float* bv_ = head ? xb_ : cb;

    const int t = threadIdx.x, lane = t & 63, w = t >> 6;
    const int r0 = blockIdx.x * 32;
    const f16x8* BP = (const f16x8*)Wpk;

    // gather + fp16x2 split staging (32 rows x 256 cols)
#pragma unroll
    for (int i = 0; i < 4; i++) {
        const int f = i * 2048 + t * 4;
        const int row = f >> 8, col = f & 255;
        const int r = min(r0 + row, R - 1);
        const int n = idxb[r];
        const int b = r / 100;
        const f32x4 v = *(const f32x4*)&flat[((size_t)b * 5376 + n) * 256 + col];
        f16x4 h, m;
        h[0] = (_Float16)v[0]; m[0] = (_Float16)(v[0] - (float)h[0]);
        h[1] = (_Float16)v[1]; m[1] = (_Float16)(v[1] - (float)h[1]);
        h[2] = (_Float16)v[2]; m[2] = (_Float16)(v[2] - (float)h[2]);
        h[3] = (_Float16)v[3]; m[3] = (_Float16)(v[3] - (float)h[3]);
        *(f16x4*)&Xh[row * XS2 + col] = h;
        *(f16x4*)&Xm[row * XS2 + col] = m;
    }

    f32x4 acc[2][2];
    const int ar = lane & 15, quad = lane >> 4;

    for (int l = 0; l < 4; l++) {
        __syncthreads();
#pragma unroll
        for (int mt = 0; mt < 2; mt++)
#pragma unroll
            for (int q = 0; q < 2; q++) acc[mt][q] = (f32x4){0.f, 0.f, 0.f, 0.f};
#pragma unroll
        for (int ks = 0; ks < 8; ks++) {
            const int ao = ks * 32 + quad * 8;
            f16x8 bh[2], bm[2];
#pragma unroll
            for (int q = 0; q < 2; q++) {
                const int g = (l * 8 + ks) * 16 + (w * 2 + q);
                bh[q] = BP[(g * 2 + 0) * 64 + lane];
                bm[q] = BP[(g * 2 + 1) * 64 + lane];
            }
            f16x8 ah[2], am[2];
#pragma unroll
            for (int mt = 0; mt < 2; mt++) {
                ah[mt] = *(const f16x8*)&Xh[(ar + mt * 16) * XS2 + ao];
                am[mt] = *(const f16x8*)&Xm[(ar + mt * 16) * XS2 + ao];
            }
#pragma unroll
            for (int q = 0; q < 2; q++)
#pragma unroll
                for (int mt = 0; mt < 2; mt++)
                    acc[mt][q] = __builtin_amdgcn_mfma_f32_16x16x32_f16(ah[mt], bh[q], acc[mt][q], 0, 0, 0);
#pragma unroll
            for (int q = 0; q < 2; q++)
#pragma unroll
                for (int mt = 0; mt < 2; mt++)
                    acc[mt][q] = __builtin_amdgcn_mfma_f32_16x16x32_f16(ah[mt], bm[q], acc[mt][q], 0, 0, 0);
#pragma unroll
            for (int q = 0; q < 2; q++)
#pragma unroll
                for (int mt = 0; mt < 2; mt++)
                    acc[mt][q] = __builtin_amdgcn_mfma_f32_16x16x32_f16(am[mt], bh[q], acc[mt][q], 0, 0, 0);
#pragma unroll
            for (int q = 0; q < 2; q++)
#pragma unroll
                for (int mt = 0; mt < 2; mt++)
                    acc[mt][q] = __builtin_amdgcn_mfma_f32_16x16x32_f16(am[mt], bm[q], acc[mt][q], 0, 0, 0);
        }

        float bcol[2];
#pragma unroll
        for (int q = 0; q < 2; q++) bcol[q] = bsv[l * 256 + (w * 2 + q) * 16 + ar];
#pragma unroll
        for (int mt = 0; mt < 2; mt++)
#pragma unroll
            for (int q = 0; q < 2; q++)
#pragma unroll
                for (int r = 0; r < 4; r++) acc[mt][q][r] += bcol[q];

#pragma unroll
        for (int mt = 0; mt < 2; mt++)
#pragma unroll
            for (int r = 0; r < 4; r++) {
                float s  = acc[mt][0][r] + acc[mt][1][r];
                float ss = acc[mt][0][r] * acc[mt][0][r] + acc[mt][1][r] * acc[mt][1][r];
#pragma unroll
                for (int off = 1; off < 16; off <<= 1) {
                    s  += __shfl_xor(s, off, 64);
                    ss += __shfl_xor(ss, off, 64);
                }
                if (ar == 0) {
                    const int row = mt * 16 + quad * 4 + r;
                    red[row * 9 + w] = s;
                    red[288 + row * 9 + w] = ss;
                }
            }
        __syncthreads();
        if (t < 32) {
            float s = 0.f, ss = 0.f;
#pragma unroll
            for (int q = 0; q < 8; q++) { s += red[t * 9 + q]; ss += red[288 + t * 9 + q]; }
            const float mn = s * (1.0f / 256.0f);
            float2 sv;
            sv.x = mn;
            sv.y = rsqrtf(ss * (1.0f / 256.0f) - mn * mn + LN_EPS);
            stat[t] = sv;
        }
        __syncthreads();

#pragma unroll
        for (int q = 0; q < 2; q++) {
            const int col = (w * 2 + q) * 16 + ar;
            const float gc = gv_[l * 256 + col], bc = bv_[l * 256 + col];
#pragma unroll
            for (int mt = 0; mt < 2; mt++)
#pragma unroll
                for (int r = 0; r < 4; r++) {
                    const int row = mt * 16 + quad * 4 + r;
                    const float2 sv = stat[row];
                    float v = (acc[mt][q][r] - sv.x) * sv.y * gc + bc;
                    v = v * sigmoid_fast(v);
                    const _Float16 h = (_Float16)v;
                    Xh[row * XS2 + col] = h;
                    Xm[row * XS2 + col] = (_Float16)(v - (float)h);
                }
        }
    }
    __syncthreads();   // finals use cross-wave row mapping

    const int m = t >> 3, g = t & 7;   // 8 threads per row; rows 0..31 -> t<256
    const int r = r0 + m;
    if (head == 0) {
        if (m < 32) {
            const int jbase = g * 10;
            float lg[10];
#pragma unroll
            for (int jj = 0; jj < 10; jj++) lg[jj] = cbf[jbase + jj];
            for (int k = 0; k < 256; k++) {
                const float hv = (float)Xh[m * XS2 + k] + (float)Xm[m * XS2 + k];
                const float* wr = &cWf[k * 80 + jbase];
#pragma unroll
                for (int jj = 0; jj < 10; jj++) lg[jj] += hv * wr[jj];
            }
            float best = lg[0]; int bj = jbase;
#pragma unroll
            for (int jj = 1; jj < 10; jj++)
                if (lg[jj] > best) { best = lg[jj]; bj = jbase + jj; }
#pragma unroll
            for (int off = 1; off < 8; off <<= 1) {
                const float ob = __shfl_xor(best, off, 64);
                const int oj = __shfl_xor(bj, off, 64);
                if (ob > best || (ob == best && oj < bj)) { best = ob; bj = oj; }
            }
            if (g == 0 && r < R) out[B + B * 100 + r] = (float)bj;
        }
    } else {
        if (m < 32) {
            float a[4] = {0.f, 0.f, 0.f, 0.f};
#pragma unroll
            for (int k4 = 0; k4 < 8; k4++) {
                const int kb = g * 32 + k4 * 4;
#pragma unroll
                for (int j = 0; j < 4; j++) {
                    const float hv = (float)Xh[m * XS2 + kb + j] + (float)Xm[m * XS2 + kb + j];
                    const float4 wf = *(const float4*)&xWf[(kb + j) * 4];
                    a[0] += hv * wf.x; a[1] += hv * wf.y;
                    a[2] += hv * wf.z; a[3] += hv * wf.w;
                }
            }
#pragma unroll
            for (int off = 1; off < 8; off <<= 1) {
                a[0] += __shfl_xor(a[0], off, 64);
                a[1] += __shfl_xor(a[1], off, 64);
                a[2] += __shfl_xor(a[2], off, 64);
                a[3] += __shfl_xor(a[3], off, 64);
            }
            if (g == 0 && r < R) {
                const float e0 = a[0] + xbf[0], e1 = a[1] + xbf[1];
                const float e2 = a[2] + xbf[2], e3 = a[3] + xbf[3];
                const int n = idxb[r];
                int base, gw, gh;
                if (n < 4096)      { base = 0;    gw = 64; gh = 64; }
                else if (n < 5120) { base = 4096; gw = 32; gh = 32; }
                else               { base = 5120; gw = 16; gh = 16; }
                const int p = n - base;
                const int py = p / gw, px = p % gw;
                const float gx = (px + 0.5f) / gw;
                const float gy = (py + 0.5f) / gh;
                const float fw = (float)full_w[0], fh = (float)full_h[0];
                const int ob = B + 2 * B * 100;
                out[ob + r * 4 + 0] = (gx - 0.5f / gw * expf(e0)) * fw;
                out[ob + r * 4 + 1] = (gy - 0.5f / gh * expf(e1)) * fh;
                out[ob + r * 4 + 2] = (gx + 0.5f / gw * expf(e2)) * fw;
                out[ob + r * 4 + 3] = (gy + 0.5f / gh * expf(e3)) * fh;
            }
        }
    }
}

extern "C" void kernel_launch(void* const* d_in, const int* in_sizes, int n_in,
                              void* d_out, int out_size, void* d_ws, size_t ws_size,
                              hipStream_t stream)
{
    const float* x3  = (const float*)d_in[0];
    const float* x4  = (const float*)d_in[1];
    const float* x5  = (const float*)d_in[2];
    const float* lw3 = (const float*)d_in[3];
    const float* lw4 = (const float*)d_in[4];
    const float* lw5 = (const float*)d_in[5];
    const float* bng = (const float*)d_in[6];
    const float* bnb = (const float*)d_in[7];
    const float* bnm = (const float*)d_in[8];
    const float* bnv = (const float*)d_in[9];

    const float* loc_Ws  = (const float*)d_in[10];
    const float* loc_bs  = (const float*)d_in[11];
    const float* loc_lng = (const float*)d_in[12];
    const float* loc_lnb = (const float*)d_in[13];
    const float* loc_Wf  = (const float*)d_in[14];
    const float* loc_bf  = (const float*)d_in[15];

    const float* cls_Ws  = (const float*)d_in[16];
    const float* cls_bs  = (const float*)d_in[17];
    const float* cls_lng = (const float*)d_in[18];
    const float* cls_lnb = (const float*)d_in[19];
    const float* cls_Wf  = (const float*)d_in[20];
    const float* cls_bf  = (const float*)d_in[21];

    const float* box_Ws  = (const float*)d_in[22];
    const float* box_bs  = (const float*)d_in[23];
    const float* box_lng = (const float*)d_in[24];
    const float* box_lnb = (const float*)d_in[25];
    const float* box_Wf  = (const float*)d_in[26];
    const float* box_bf  = (const float*)d_in[27];

    const int* full_h = (const int*)d_in[28];
    const int* full_w = (const int*)d_in[29];

    const int B = in_sizes[0] / (256 * 64 * 64);   // 8
    const int M = B * 5376;                        // 43008
    const int R = B * 100;                         // 800

    float* ws = (float*)d_ws;
    float* flat = ws;                                  // [M*256] fp32
    float* loc  = flat + (size_t)M * 256;              // [M]
    int*   idxb = (int*)(loc + M);                     // [R] (padded 1024)
    _Float16* locP = (_Float16*)(idxb + 1024);         // 1 MB each
    _Float16* clsP = locP + 524288;
    _Float16* boxP = clsP + 524288;
    _Float16* w3   = boxP + 524288;                    // 256KB
    _Float16* w4   = w3 + 131072;                      // 512KB
    _Float16* w5   = w4 + 262144;                      // 1MB

    float* out = (float*)d_out;
    const dim3 blk(256);

    // 0) all weight prep (1 launch)
    prep_all<<<608, blk, 0, stream>>>(loc_Ws, cls_Ws, box_Ws, lw3, lw4, lw5,
                                      locP, clsP, boxP, w3, w4, w5);

    // 1) fused lateral conv+BN + loc MLP -> flat + logits (lv5 blocks first)
    lateral_loc<<<B * 168, dim3(512), 0, stream>>>(
        x3, x4, x5, w3, w4, w5, bng, bnb, bnm, bnv,
        locP, loc_bs, loc_lng, loc_lnb, loc_Wf, loc_bf,
        flat, loc, B);

    // 2) top-k (radix select)
    topk_kernel<<<B, blk, 0, stream>>>(loc, idxb, out, B);

    // 3) both heads (fp16x2 MFMA core, 4 products), 32-row blocks
    heads_mlp_f16<<<dim3(R / 32, 2), dim3(512), 0, stream>>>(
        flat, idxb,
        clsP, cls_bs, cls_lng, cls_lnb, cls_Wf, cls_bf,
        boxP, box_bs, box_lng, box_lnb, box_Wf, box_bf,
        full_h, full_w, out, B, R);
}

// Round 15
// 351.400 us; speedup vs baseline: 1.5247x; 1.0059x over previous
//
#include <hip/hip_runtime.h>
#include <math.h>

#define LN_EPS 1e-5f
#define XS2 264   // padded X row stride in halves (132 dwords ≡ 4 mod 32 banks)

typedef __attribute__((ext_vector_type(8))) _Float16 f16x8;
typedef __attribute__((ext_vector_type(4))) _Float16 f16x4;
typedef __attribute__((ext_vector_type(4))) float f32x4;

__device__ __forceinline__ float sigmoidf(float x) { return 1.0f / (1.0f + expf(-x)); }
// fast silu-grade sigmoid: v_exp + v_rcp, ~1e-7 rel err (<< fp16x2 noise floor)
__device__ __forceinline__ float sigmoid_fast(float x) {
    return __builtin_amdgcn_rcpf(1.0f + __expf(-x));
}

// ---------------------------------------------------------------------------
// Fused weight prep: loc/cls/box MLP stacks + 3 lateral weights -> hi/lo fp16
// fragment-packed (frag g, plane p: f16x8 unit (g*2+p)*64+lane).
// MLP stacks: g=(l*8+ks)*16+nt, 512 groups each. Laterals: g=ks*16+nt.
// Grid 608 x 256 (2432 groups).
// ---------------------------------------------------------------------------
__global__ __launch_bounds__(256) void prep_all(
    const float* __restrict__ locW, const float* __restrict__ clsW,
    const float* __restrict__ boxW,
    const float* __restrict__ lw3, const float* __restrict__ lw4,
    const float* __restrict__ lw5,
    _Float16* __restrict__ locP, _Float16* __restrict__ clsP,
    _Float16* __restrict__ boxP,
    _Float16* __restrict__ w3, _Float16* __restrict__ w4,
    _Float16* __restrict__ w5)
{
    const int t = threadIdx.x, lane = t & 63;
    const int gi = blockIdx.x * 4 + (t >> 6);
    const float* W; _Float16* P; int g, Cin = 0; bool mlp;
    if (gi < 512)        { W = locW; P = locP; g = gi;        mlp = true; }
    else if (gi < 1024)  { W = clsW; P = clsP; g = gi - 512;  mlp = true; }
    else if (gi < 1536)  { W = boxW; P = boxP; g = gi - 1024; mlp = true; }
    else if (gi < 1664)  { W = lw3;  P = w3;   g = gi - 1536; mlp = false; Cin = 256; }
    else if (gi < 1920)  { W = lw4;  P = w4;   g = gi - 1664; mlp = false; Cin = 512; }
    else                 { W = lw5;  P = w5;   g = gi - 1920; mlp = false; Cin = 1024; }

    _Float16 h[8], m[8];
    if (mlp) {
        const int nt = g & 15, ks = (g >> 4) & 7, l = g >> 7;
        const int n = nt * 16 + (lane & 15);
        const int k0 = ks * 32 + (lane >> 4) * 8;
#pragma unroll
        for (int j = 0; j < 8; j++) {
            const float f = W[(size_t)l * 65536 + (size_t)(k0 + j) * 256 + n];
            h[j] = (_Float16)f;
            m[j] = (_Float16)(f - (float)h[j]);
        }
    } else {
        const int nt = g & 15, ks = g >> 4;
        const int n = nt * 16 + (lane & 15);
        const int k0 = ks * 32 + (lane >> 4) * 8;
#pragma unroll
        for (int j = 0; j < 8; j++) {
            const float f = W[(size_t)n * Cin + k0 + j];
            h[j] = (_Float16)f;
            m[j] = (_Float16)(f - (float)h[j]);
        }
    }
    const size_t oh = ((size_t)(g * 2 + 0) * 64 + lane) * 8;
    const size_t om = ((size_t)(g * 2 + 1) * 64 + lane) * 8;
#pragma unroll
    for (int j = 0; j < 8; j++) { P[oh + j] = h[j]; P[om + j] = m[j]; }
}

// ---------------------------------------------------------------------------
// FUSED lateral conv+BN + loc MLP. 32 px rows per block, 512 thr (8 waves).
// Part A: 1-deep register pipeline (macro form; lambdas defeat SROA ->
// scratch, round 6). Part B: proven 32-row loc core, coop LN stats.
// SETTLED (rounds 7-12, bilaterally bracketed): launch_bounds min-waves sets
// the unified VGPR+AGPR budget; (512,4)/1-deep/64reg@38%occ = 157us BEATS
// (512,2)/2-deep/80reg@20%occ = 210us and every spill configuration. TLP >
// ILP for this kernel (barrier-synced Part B needs wave diversity). Do not
// revisit prefetch depth or bounds without restructuring the algorithm.
// Long lv5 blocks (CH=32) first. Grid B*168.
// ---------------------------------------------------------------------------
__global__ __launch_bounds__(512, 4) void lateral_loc(
    const float* __restrict__ x3, const float* __restrict__ x4,
    const float* __restrict__ x5,
    const _Float16* __restrict__ w3, const _Float16* __restrict__ w4,
    const _Float16* __restrict__ w5,
    const float* __restrict__ bng, const float* __restrict__ bnb,
    const float* __restrict__ bnm, const float* __restrict__ bnv,
    const _Float16* __restrict__ Wpk, const float* __restrict__ bs,
    const float* __restrict__ lng, const float* __restrict__ lnb,
    const float* __restrict__ Wf, const float* __restrict__ bfp,
    float* __restrict__ flat, float* __restrict__ logits, int B)
{
    __shared__ _Float16 Xh[32 * XS2];
    __shared__ _Float16 Xm[32 * XS2];
    __shared__ float red[2 * 32 * 9];   // [plane][row][wave], stride 9
    __shared__ float2 stat[32];         // (mean, rstd) per row

    const int bid = blockIdx.x;
    const int n5 = B * 8, n4 = B * 32;
    const float* x; const _Float16* wp; int CH, HW, base, rb, lv;
    if (bid < n5)            { x = x5; wp = w5; CH = 32; HW = 256;  base = 5120; rb = bid * 32;             lv = 2; }
    else if (bid < n5 + n4)  { x = x4; wp = w4; CH = 16; HW = 1024; base = 4096; rb = (bid - n5) * 32;      lv = 1; }
    else                     { x = x3; wp = w3; CH = 8;  HW = 4096; base = 0;    rb = (bid - n5 - n4) * 32; lv = 0; }
    const int b    = rb / HW;
    const int px0  = rb % HW;
    const int row0 = b * 5376 + base + px0;

    const int t = threadIdx.x, lane = t & 63, w = t >> 6;
    const int ar = lane & 15, quad = lane >> 4;
    const f16x8* WBP = (const f16x8*)wp;
    const f16x8* BP  = (const f16x8*)Wpk;

    f32x4 acc[2][2];
#pragma unroll
    for (int mt = 0; mt < 2; mt++)
#pragma unroll
        for (int q = 0; q < 2; q++) acc[mt][q] = (f32x4){0.f, 0.f, 0.f, 0.f};

    // ---- Part A: lateral conv, software-pipelined (macro form) ----
    {
        const float* xb = x + (size_t)b * (CH * 32) * HW;
        const float* xq = xb + (size_t)(quad * 8) * HW + px0 + ar;

        float xA[16], xB[16];

#define LOADX_(ks, X)                                                         \
        {                                                                     \
            const float* xp_ = xq + (size_t)((ks) * 32) * HW;                 \
            _Pragma("unroll")                                                 \
            for (int mt_ = 0; mt_ < 2; mt_++) {                               \
                _Pragma("unroll")                                             \
                for (int j_ = 0; j_ < 8; j_++)                                \
                    X[mt_ * 8 + j_] = xp_[(size_t)j_ * HW + mt_ * 16];        \
            }                                                                 \
        }

#define STEP_(ks, X)                                                          \
        {                                                                     \
            f16x8 wh_[2], wm_[2];                                             \
            _Pragma("unroll")                                                 \
            for (int q_ = 0; q_ < 2; q_++) {                                  \
                const int g_ = (ks) * 16 + (w * 2 + q_);                      \
                wh_[q_] = WBP[(g_ * 2 + 0) * 64 + lane];                      \
                wm_[q_] = WBP[(g_ * 2 + 1) * 64 + lane];                      \
            }                                                                 \
            f16x8 aH_[2], aM_[2];                                             \
            _Pragma("unroll")                                                 \
            for (int mt_ = 0; mt_ < 2; mt_++) {                               \
                _Pragma("unroll")                                             \
                for (int p_ = 0; p_ < 4; p_++) {                              \
                    const float v0_ = X[mt_ * 8 + 2 * p_];                    \
                    const float v1_ = X[mt_ * 8 + 2 * p_ + 1];                \
                    const auto h2_ = __builtin_amdgcn_cvt_pkrtz(v0_, v1_);    \
                    const auto m2_ = __builtin_amdgcn_cvt_pkrtz(               \
                        v0_ - (float)h2_[0], v1_ - (float)h2_[1]);            \
                    aH_[mt_][2 * p_]     = (_Float16)h2_[0];                  \
                    aH_[mt_][2 * p_ + 1] = (_Float16)h2_[1];                  \
                    aM_[mt_][2 * p_]     = (_Float16)m2_[0];                  \
                    aM_[mt_][2 * p_ + 1] = (_Float16)m2_[1];                  \
                }                                                             \
            }                                                                 \
            _Pragma("unroll")                                                 \
            for (int q_ = 0; q_ < 2; q_++)                                    \
                _Pragma("unroll")                                             \
                for (int mt_ = 0; mt_ < 2; mt_++)                             \
                    acc[mt_][q_] = __builtin_amdgcn_mfma_f32_16x16x32_f16(    \
                        aH_[mt_], wh_[q_], acc[mt_][q_], 0, 0, 0);            \
            _Pragma("unroll")                                                 \
            for (int q_ = 0; q_ < 2; q_++)                                    \
                _Pragma("unroll")                                             \
                for (int mt_ = 0; mt_ < 2; mt_++)                             \
                    acc[mt_][q_] = __builtin_amdgcn_mfma_f32_16x16x32_f16(    \
                        aH_[mt_], wm_[q_], acc[mt_][q_], 0, 0, 0);            \
            _Pragma("unroll")                                                 \
            for (int q_ = 0; q_ < 2; q_++)                                    \
                _Pragma("unroll")                                             \
                for (int mt_ = 0; mt_ < 2; mt_++)                             \
                    acc[mt_][q_] = __builtin_amdgcn_mfma_f32_16x16x32_f16(    \
                        aM_[mt_], wh_[q_], acc[mt_][q_], 0, 0, 0);            \
        }

        LOADX_(0, xA);
        for (int ks = 0; ks < CH; ks += 2) {
            LOADX_(ks + 1, xB);              // in flight over STEP(ks)
            STEP_(ks, xA);
            if (ks + 2 < CH) LOADX_(ks + 2, xA);
            STEP_(ks + 1, xB);
        }
#undef LOADX_
#undef STEP_
    }

    // BN epilogue -> flat (fp32, cached write-back) + Xh/Xm LDS split
#pragma unroll
    for (int q = 0; q < 2; q++) {
        const int col = (w * 2 + q) * 16 + ar;
        const float sc = bng[lv * 256 + col] * rsqrtf(bnv[lv * 256 + col] + LN_EPS);
        const float mh = bnm[lv * 256 + col];
        const float bb = bnb[lv * 256 + col];
#pragma unroll
        for (int mt = 0; mt < 2; mt++)
#pragma unroll
            for (int r = 0; r < 4; r++) {
                const int lr = mt * 16 + quad * 4 + r;
                const float v = (acc[mt][q][r] - mh) * sc + bb;
                flat[((size_t)row0 + lr) * 256 + col] = v;
                const _Float16 h = (_Float16)v;
                Xh[lr * XS2 + col] = h;
                Xm[lr * XS2 + col] = (_Float16)(v - (float)h);
            }
    }

    // ---- Part B: loc MLP (proven 32-row core) ----
    for (int l = 0; l < 4; l++) {
        __syncthreads();
#pragma unroll
        for (int mt = 0; mt < 2; mt++)
#pragma unroll
            for (int q = 0; q < 2; q++) acc[mt][q] = (f32x4){0.f, 0.f, 0.f, 0.f};
#pragma unroll
        for (int ks = 0; ks < 8; ks++) {
            const int ao = ks * 32 + quad * 8;
            f16x8 bh[2], bm[2];
#pragma unroll
            for (int q = 0; q < 2; q++) {
                const int g = (l * 8 + ks) * 16 + (w * 2 + q);
                bh[q] = BP[(g * 2 + 0) * 64 + lane];
                bm[q] = BP[(g * 2 + 1) * 64 + lane];
            }
            f16x8 ah[2], am[2];
#pragma unroll
            for (int mt = 0; mt < 2; mt++) {
                ah[mt] = *(const f16x8*)&Xh[(ar + mt * 16) * XS2 + ao];
                am[mt] = *(const f16x8*)&Xm[(ar + mt * 16) * XS2 + ao];
            }
#pragma unroll
            for (int q = 0; q < 2; q++)
#pragma unroll
                for (int mt = 0; mt < 2; mt++)
                    acc[mt][q] = __builtin_amdgcn_mfma_f32_16x16x32_f16(ah[mt], bh[q], acc[mt][q], 0, 0, 0);
#pragma unroll
            for (int q = 0; q < 2; q++)
#pragma unroll
                for (int mt = 0; mt < 2; mt++)
                    acc[mt][q] = __builtin_amdgcn_mfma_f32_16x16x32_f16(ah[mt], bm[q], acc[mt][q], 0, 0, 0);
#pragma unroll
            for (int q = 0; q < 2; q++)
#pragma unroll
                for (int mt = 0; mt < 2; mt++)
                    acc[mt][q] = __builtin_amdgcn_mfma_f32_16x16x32_f16(am[mt], bh[q], acc[mt][q], 0, 0, 0);
        }

        float bcol[2];
#pragma unroll
        for (int q = 0; q < 2; q++) bcol[q] = bs[l * 256 + (w * 2 + q) * 16 + ar];
#pragma unroll
        for (int mt = 0; mt < 2; mt++)
#pragma unroll
            for (int q = 0; q < 2; q++)
#pragma unroll
                for (int r = 0; r < 4; r++) acc[mt][q][r] += bcol[q];

        // phase 1: per-wave partial (sum over this wave's 32 cols)
#pragma unroll
        for (int mt = 0; mt < 2; mt++)
#pragma unroll
            for (int r = 0; r < 4; r++) {
                float s  = acc[mt][0][r] + acc[mt][1][r];
                float ss = acc[mt][0][r] * acc[mt][0][r] + acc[mt][1][r] * acc[mt][1][r];
#pragma unroll
                for (int off = 1; off < 16; off <<= 1) {
                    s  += __shfl_xor(s, off, 64);
                    ss += __shfl_xor(ss, off, 64);
                }
                if (ar == 0) {
                    const int row = mt * 16 + quad * 4 + r;
                    red[row * 9 + w] = s;
                    red[288 + row * 9 + w] = ss;
                }
            }
        __syncthreads();

        // phase 2: cooperative stats (one thread per row)
        if (t < 32) {
            float s = 0.f, ss = 0.f;
#pragma unroll
            for (int q = 0; q < 8; q++) { s += red[t * 9 + q]; ss += red[288 + t * 9 + q]; }
            const float mn = s * (1.0f / 256.0f);
            float2 sv;
            sv.x = mn;
            sv.y = rsqrtf(ss * (1.0f / 256.0f) - mn * mn + LN_EPS);
            stat[t] = sv;
        }
        __syncthreads();

        if (l < 3) {
            const int colb = w * 32;
            float gc[2], bc[2];
#pragma unroll
            for (int q = 0; q < 2; q++) {
                const int col = colb + q * 16 + ar;
                gc[q] = lng[l * 256 + col];
                bc[q] = lnb[l * 256 + col];
            }
#pragma unroll
            for (int mt = 0; mt < 2; mt++)
#pragma unroll
                for (int r = 0; r < 4; r++) {
                    const int row = mt * 16 + quad * 4 + r;
                    const float2 sv = stat[row];
#pragma unroll
                    for (int q = 0; q < 2; q++) {
                        float v = (acc[mt][q][r] - sv.x) * sv.y * gc[q] + bc[q];
                        v = v * sigmoid_fast(v);
                        const _Float16 h = (_Float16)v;
                        const int col = colb + q * 16 + ar;
                        Xh[row * XS2 + col] = h;
                        Xm[row * XS2 + col] = (_Float16)(v - (float)h);
                    }
                }
        } else {
            float gc[2], bc[2], wf[2];
#pragma unroll
            for (int q = 0; q < 2; q++) {
                const int col = w * 32 + q * 16 + ar;
                gc[q] = lng[3 * 256 + col];
                bc[q] = lnb[3 * 256 + col];
                wf[q] = Wf[col];
            }
#pragma unroll
            for (int mt = 0; mt < 2; mt++)
#pragma unroll
                for (int r = 0; r < 4; r++) {
                    const int row = mt * 16 + quad * 4 + r;
                    const float2 sv = stat[row];
                    float p = 0.f;
#pragma unroll
                    for (int q = 0; q < 2; q++) {
                        float v = (acc[mt][q][r] - sv.x) * sv.y * gc[q] + bc[q];
                        p += (v * sigmoid_fast(v)) * wf[q];
                    }
#pragma unroll
                    for (int off = 1; off < 16; off <<= 1) p += __shfl_xor(p, off, 64);
                    if (ar == 0) red[row * 9 + w] = p;
                }
            __syncthreads();
            if (t < 32) {
                float s = 0.f;
#pragma unroll
                for (int q = 0; q < 8; q++) s += red[t * 9 + q];
                logits[row0 + t] = s + bfp[0];
            }
        }
    }
}

// ---------------------------------------------------------------------------
// Top-100 per batch (sorted desc, ties -> lower index). Grid B, block 256.
// v3: 4-pass radix select (8 bits/pass) on monotonic uint keys -> exact
// rank-100 value in 4 parallel histogram passes; then one compaction pass
// + O(100x100) broadcast rank to emit sorted output.
// ---------------------------------------------------------------------------
__global__ __launch_bounds__(256) void topk_kernel(
    const float* __restrict__ logits, int* __restrict__ idx_out,
    float* __restrict__ out, int B)
{
    __shared__ unsigned int keys[5376];
    __shared__ int hist[256];
    __shared__ unsigned int selk[128];
    __shared__ int seli[128];
    __shared__ int eqi[1024];
    __shared__ int ctr[4];           // 0: cnt>Kthr slots, 1: eq count, 2: score>0.5 count
    __shared__ unsigned int bc[2];   // 0: prefix, 1: need

    const int t = threadIdx.x, b = blockIdx.x;

    // load + monotonic transform (order-preserving float -> uint)
#pragma unroll
    for (int k = 0; k < 21; k++) {
        const int i = t + k * 256;
        const unsigned int u = __float_as_uint(logits[b * 5376 + i]);
        keys[i] = (u & 0x80000000u) ? ~u : (u | 0x80000000u);
    }
    if (t == 0) { ctr[0] = 0; ctr[1] = 0; ctr[2] = 0; }

    unsigned int prefix = 0, pmask = 0;
    int need = 100;

    for (int pass = 0; pass < 4; pass++) {
        const int shift = 24 - pass * 8;
        hist[t] = 0;
        __syncthreads();
#pragma unroll
        for (int k = 0; k < 21; k++) {
            const unsigned int key = keys[t + k * 256];
            if (((key ^ prefix) & pmask) == 0)
                atomicAdd(&hist[(key >> shift) & 255], 1);
        }
        __syncthreads();
        if (t < 64) {
            const int h0 = hist[t * 4 + 0], h1 = hist[t * 4 + 1];
            const int h2 = hist[t * 4 + 2], h3 = hist[t * 4 + 3];
            const int sl = h0 + h1 + h2 + h3;
            // inclusive prefix sum across lanes
            int P = sl;
#pragma unroll
            for (int off = 1; off < 64; off <<= 1) {
                const int o = __shfl_up(P, off, 64);
                if (t >= off) P += o;
            }
            const int total = __shfl(P, 63, 64);
            const int suff = total - P + sl;          // sum over lane groups >= t
            const unsigned long long m = __ballot(suff >= need);
            const int t0 = 63 - __clzll(m);
            if (t == t0) {
                const int f1 = suff - h0;
                const int f2 = f1 - h1;
                const int f3 = f2 - h2;
                int bv, G;
                if (f3 >= need)      { bv = 3; G = f3 - h3; }
                else if (f2 >= need) { bv = 2; G = f3; }
                else if (f1 >= need) { bv = 1; G = f2; }
                else                 { bv = 0; G = f1; }
                bc[0] = prefix | ((unsigned int)(4 * t0 + bv) << shift);
                bc[1] = (unsigned int)(need - G);
            }
        }
        __syncthreads();
        prefix = bc[0];
        need = (int)bc[1];
        pmask = (pmask >> 8) | 0xFF000000u;
        __syncthreads();
    }
    const unsigned int Kthr = prefix;   // exact key of the rank-100 value
    const int needF = need;             // how many == Kthr to take (lowest idx first)

    // compaction
#pragma unroll
    for (int k = 0; k < 21; k++) {
        const int i = t + k * 256;
        const unsigned int key = keys[i];
        if (key > Kthr) {
            const int p = atomicAdd(&ctr[0], 1);
            selk[p] = key; seli[p] = i;
        } else if (key == Kthr) {
            const int p = atomicAdd(&ctr[1], 1);
            if (p < 1024) eqi[p] = i;
        }
    }
    __syncthreads();
    const int cg = ctr[0], ce = ctr[1];
    // append `needF` lowest-index equal elements
    for (int i = t; i < ce && i < 1024; i += 256) {
        const int my = eqi[i];
        int rank = 0;
        for (int j = 0; j < ce && j < 1024; j++) rank += (eqi[j] < my);
        if (rank < needF) { selk[cg + rank] = Kthr; seli[cg + rank] = my; }
    }
    __syncthreads();

    // rank the 100 selected (value desc, index asc) and emit
    if (t < 100) {
        const unsigned int myk = selk[t];
        const int myi = seli[t];
        int rank = 0;
        for (int j = 0; j < 100; j++) {
            const unsigned int kj = selk[j];
            const int ij = seli[j];
            rank += (kj > myk) || (kj == myk && ij < myi);
        }
        const unsigned int u = (myk & 0x80000000u) ? (myk & 0x7fffffffu) : ~myk;
        const float f = __uint_as_float(u);
        idx_out[b * 100 + rank] = myi;
        out[B + b * 100 + rank] = sigmoidf(f);
        if (f > 0.0f) atomicAdd(&ctr[2], 1);
    }
    __syncthreads();
    if (t == 0) out[b] = (float)ctr[2];
}

// ---------------------------------------------------------------------------
// Fused heads on the fp16x2 MFMA core (4 products for max margin):
// gather + 4x [GEMM+LN+SiLU] + finals.
// v4: 16-row blocks -> grid (R/16=50, 2) = 100 blocks (r14: 26->50 blocks
// gave -48us, near-linear latency scaling; push CU coverage again). Each
// wave's 16 ar-lanes cover all 16 rows (mt dimension collapsed, acc[2]).
// LDS ~18 KB. Finals: 8 thr/row, t<128.
// ---------------------------------------------------------------------------
__global__ __launch_bounds__(512) void heads_mlp_f16(
    const float* __restrict__ flat, const int* __restrict__ idxb,
    const _Float16* __restrict__ cWpk, const float* __restrict__ cbs,
    const float* __restrict__ cg, const float* __restrict__ cb,
    const float* __restrict__ cWf, const float* __restrict__ cbf,
    const _Float16* __restrict__ xWpk, const float* __restrict__ xbs,
    const float* __restrict__ xg, const float* __restrict__ xb_,
    const float* __restrict__ xWf, const float* __restrict__ xbf,
    const int* __restrict__ full_h, const int* __restrict__ full_w,
    float* __restrict__ out, int B, int R)
{
    __shared__ _Float16 Xh[16 * XS2];
    __shared__ _Float16 Xm[16 * XS2];
    __shared__ float red[2 * 16 * 9];
    __shared__ float2 stat[16];
    const int head = blockIdx.y;
    const _Float16* Wpk = head ? xWpk : cWpk;
    const float* bsv = head ? xbs : cbs;
    const float* gv_ = head ? xg : cg;
    const float* bv_ = head ? xb_ : cb;

    const int t = threadIdx.x, lane = t & 63, w = t >> 6;
    const int r0 = blockIdx.x * 16;
    const f16x8* BP = (const f16x8*)Wpk;

    // gather + fp16x2 split staging (16 rows x 256 cols)
#pragma unroll
    for (int i = 0; i < 2; i++) {
        const int f = i * 2048 + t * 4;
        const int row = f >> 8, col = f & 255;
        const int r = min(r0 + row, R - 1);
        const int n = idxb[r];
        const int b = r / 100;
        const f32x4 v = *(const f32x4*)&flat[((size_t)b * 5376 + n) * 256 + col];
        f16x4 h, m;
        h[0] = (_Float16)v[0]; m[0] = (_Float16)(v[0] - (float)h[0]);
        h[1] = (_Float16)v[1]; m[1] = (_Float16)(v[1] - (float)h[1]);
        h[2] = (_Float16)v[2]; m[2] = (_Float16)(v[2] - (float)h[2]);
        h[3] = (_Float16)v[3]; m[3] = (_Float16)(v[3] - (float)h[3]);
        *(f16x4*)&Xh[row * XS2 + col] = h;
        *(f16x4*)&Xm[row * XS2 + col] = m;
    }

    f32x4 acc[2];
    const int ar = lane & 15, quad = lane >> 4;

    for (int l = 0; l < 4; l++) {
        __syncthreads();
#pragma unroll
        for (int q = 0; q < 2; q++) acc[q] = (f32x4){0.f, 0.f, 0.f, 0.f};
#pragma unroll
        for (int ks = 0; ks < 8; ks++) {
            const int ao = ks * 32 + quad * 8;
            f16x8 bh[2], bm[2];
#pragma unroll
            for (int q = 0; q < 2; q++) {
                const int g = (l * 8 + ks) * 16 + (w * 2 + q);
                bh[q] = BP[(g * 2 + 0) * 64 + lane];
                bm[q] = BP[(g * 2 + 1) * 64 + lane];
            }
            const f16x8 ah = *(const f16x8*)&Xh[ar * XS2 + ao];
            const f16x8 am = *(const f16x8*)&Xm[ar * XS2 + ao];
#pragma unroll
            for (int q = 0; q < 2; q++)
                acc[q] = __builtin_amdgcn_mfma_f32_16x16x32_f16(ah, bh[q], acc[q], 0, 0, 0);
#pragma unroll
            for (int q = 0; q < 2; q++)
                acc[q] = __builtin_amdgcn_mfma_f32_16x16x32_f16(ah, bm[q], acc[q], 0, 0, 0);
#pragma unroll
            for (int q = 0; q < 2; q++)
                acc[q] = __builtin_amdgcn_mfma_f32_16x16x32_f16(am, bh[q], acc[q], 0, 0, 0);
#pragma unroll
            for (int q = 0; q < 2; q++)
                acc[q] = __builtin_amdgcn_mfma_f32_16x16x32_f16(am, bm[q], acc[q], 0, 0, 0);
        }

        float bcol[2];
#pragma unroll
        for (int q = 0; q < 2; q++) bcol[q] = bsv[l * 256 + (w * 2 + q) * 16 + ar];
#pragma unroll
        for (int q = 0; q < 2; q++)
#pragma unroll
            for (int r = 0; r < 4; r++) acc[q][r] += bcol[q];

#pragma unroll
        for (int r = 0; r < 4; r++) {
            float s  = acc[0][r] + acc[1][r];
            float ss = acc[0][r] * acc[0][r] + acc[1][r] * acc[1][r];
#pragma unroll
            for (int off = 1; off < 16; off <<= 1) {
                s  += __shfl_xor(s, off, 64);
                ss += __shfl_xor(ss, off, 64);
            }
            if (ar == 0) {
                const int row = quad * 4 + r;
                red[row * 9 + w] = s;
                red[144 + row * 9 + w] = ss;
            }
        }
        __syncthreads();
        if (t < 16) {
            float s = 0.f, ss = 0.f;
#pragma unroll
            for (int q = 0; q < 8; q++) { s += red[t * 9 + q]; ss += red[144 + t * 9 + q]; }
            const float mn = s * (1.0f / 256.0f);
            float2 sv;
            sv.x = mn;
            sv.y = rsqrtf(ss * (1.0f / 256.0f) - mn * mn + LN_EPS);
            stat[t] = sv;
        }
        __syncthreads();

#pragma unroll
        for (int q = 0; q < 2; q++) {
            const int col = (w * 2 + q) * 16 + ar;
            const float gc = gv_[l * 256 + col], bc = bv_[l * 256 + col];
#pragma unroll
            for (int r = 0; r < 4; r++) {
                const int row = quad * 4 + r;
                const float2 sv = stat[row];
                float v = (acc[q][r] - sv.x) * sv.y * gc + bc;
                v = v * sigmoid_fast(v);
                const _Float16 h = (_Float16)v;
                Xh[row * XS2 + col] = h;
                Xm[row * XS2 + col] = (_Float16)(v - (float)h);
            }
        }
    }
    __syncthreads();   // finals use cross-wave row mapping

    const int m = t >> 3, g = t & 7;   // 8 threads per row; rows 0..15 -> t<128
    const int r = r0 + m;
    if (head == 0) {
        if (m < 16) {
            const int jbase = g * 10;
            float lg[10];
#pragma unroll
            for (int jj = 0; jj < 10; jj++) lg[jj] = cbf[jbase + jj];
            for (int k = 0; k < 256; k++) {
                const float hv = (float)Xh[m * XS2 + k] + (float)Xm[m * XS2 + k];
                const float* wr = &cWf[k * 80 + jbase];
#pragma unroll
                for (int jj = 0; jj < 10; jj++) lg[jj] += hv * wr[jj];
            }
            float best = lg[0]; int bj = jbase;
#pragma unroll
            for (int jj = 1; jj < 10; jj++)
                if (lg[jj] > best) { best = lg[jj]; bj = jbase + jj; }
#pragma unroll
            for (int off = 1; off < 8; off <<= 1) {
                const float ob = __shfl_xor(best, off, 64);
                const int oj = __shfl_xor(bj, off, 64);
                if (ob > best || (ob == best && oj < bj)) { best = ob; bj = oj; }
            }
            if (g == 0 && r < R) out[B + B * 100 + r] = (float)bj;
        }
    } else {
        if (m < 16) {
            float a[4] = {0.f, 0.f, 0.f, 0.f};
#pragma unroll
            for (int k4 = 0; k4 < 8; k4++) {
                const int kb = g * 32 + k4 * 4;
#pragma unroll
                for (int j = 0; j < 4; j++) {
                    const float hv = (float)Xh[m * XS2 + kb + j] + (float)Xm[m * XS2 + kb + j];
                    const float4 wf = *(const float4*)&xWf[(kb + j) * 4];
                    a[0] += hv * wf.x; a[1] += hv * wf.y;
                    a[2] += hv * wf.z; a[3] += hv * wf.w;
                }
            }
#pragma unroll
            for (int off = 1; off < 8; off <<= 1) {
                a[0] += __shfl_xor(a[0], off, 64);
                a[1] += __shfl_xor(a[1], off, 64);
                a[2] += __shfl_xor(a[2], off, 64);
                a[3] += __shfl_xor(a[3], off, 64);
            }
            if (g == 0 && r < R) {
                const float e0 = a[0] + xbf[0], e1 = a[1] + xbf[1];
                const float e2 = a[2] + xbf[2], e3 = a[3] + xbf[3];
                const int n = idxb[r];
                int base, gw, gh;
                if (n < 4096)      { base = 0;    gw = 64; gh = 64; }
                else if (n < 5120) { base = 4096; gw = 32; gh = 32; }
                else               { base = 5120; gw = 16; gh = 16; }
                const int p = n - base;
                const int py = p / gw, px = p % gw;
                const float gx = (px + 0.5f) / gw;
                const float gy = (py + 0.5f) / gh;
                const float fw = (float)full_w[0], fh = (float)full_h[0];
                const int ob = B + 2 * B * 100;
                out[ob + r * 4 + 0] = (gx - 0.5f / gw * expf(e0)) * fw;
                out[ob + r * 4 + 1] = (gy - 0.5f / gh * expf(e1)) * fh;
                out[ob + r * 4 + 2] = (gx + 0.5f / gw * expf(e2)) * fw;
                out[ob + r * 4 + 3] = (gy + 0.5f / gh * expf(e3)) * fh;
            }
        }
    }
}

extern "C" void kernel_launch(void* const* d_in, const int* in_sizes, int n_in,
                              void* d_out, int out_size, void* d_ws, size_t ws_size,
                              hipStream_t stream)
{
    const float* x3  = (const float*)d_in[0];
    const float* x4  = (const float*)d_in[1];
    const float* x5  = (const float*)d_in[2];
    const float* lw3 = (const float*)d_in[3];
    const float* lw4 = (const float*)d_in[4];
    const float* lw5 = (const float*)d_in[5];
    const float* bng = (const float*)d_in[6];
    const float* bnb = (const float*)d_in[7];
    const float* bnm = (const float*)d_in[8];
    const float* bnv = (const float*)d_in[9];

    const float* loc_Ws  = (const float*)d_in[10];
    const float* loc_bs  = (const float*)d_in[11];
    const float* loc_lng = (const float*)d_in[12];
    const float* loc_lnb = (const float*)d_in[13];
    const float* loc_Wf  = (const float*)d_in[14];
    const float* loc_bf  = (const float*)d_in[15];

    const float* cls_Ws  = (const float*)d_in[16];
    const float* cls_bs  = (const float*)d_in[17];
    const float* cls_lng = (const float*)d_in[18];
    const float* cls_lnb = (const float*)d_in[19];
    const float* cls_Wf  = (const float*)d_in[20];
    const float* cls_bf  = (const float*)d_in[21];

    const float* box_Ws  = (const float*)d_in[22];
    const float* box_bs  = (const float*)d_in[23];
    const float* box_lng = (const float*)d_in[24];
    const float* box_lnb = (const float*)d_in[25];
    const float* box_Wf  = (const float*)d_in[26];
    const float* box_bf  = (const float*)d_in[27];

    const int* full_h = (const int*)d_in[28];
    const int* full_w = (const int*)d_in[29];

    const int B = in_sizes[0] / (256 * 64 * 64);   // 8
    const int M = B * 5376;                        // 43008
    const int R = B * 100;                         // 800

    float* ws = (float*)d_ws;
    float* flat = ws;                                  // [M*256] fp32
    float* loc  = flat + (size_t)M * 256;              // [M]
    int*   idxb = (int*)(loc + M);                     // [R] (padded 1024)
    _Float16* locP = (_Float16*)(idxb + 1024);         // 1 MB each
    _Float16* clsP = locP + 524288;
    _Float16* boxP = clsP + 524288;
    _Float16* w3   = boxP + 524288;                    // 256KB
    _Float16* w4   = w3 + 131072;                      // 512KB
    _Float16* w5   = w4 + 262144;                      // 1MB

    float* out = (float*)d_out;
    const dim3 blk(256);

    // 0) all weight prep (1 launch)
    prep_all<<<608, blk, 0, stream>>>(loc_Ws, cls_Ws, box_Ws, lw3, lw4, lw5,
                                      locP, clsP, boxP, w3, w4, w5);

    // 1) fused lateral conv+BN + loc MLP -> flat + logits (lv5 blocks first)
    lateral_loc<<<B * 168, dim3(512), 0, stream>>>(
        x3, x4, x5, w3, w4, w5, bng, bnb, bnm, bnv,
        locP, loc_bs, loc_lng, loc_lnb, loc_Wf, loc_bf,
        flat, loc, B);

    // 2) top-k (radix select)
    topk_kernel<<<B, blk, 0, stream>>>(loc, idxb, out, B);

    // 3) both heads (fp16x2 MFMA core, 4 products), 16-row blocks
    heads_mlp_f16<<<dim3(R / 16, 2), dim3(512), 0, stream>>>(
        flat, idxb,
        clsP, cls_bs, cls_lng, cls_lnb, cls_Wf, cls_bf,
        boxP, box_bs, box_lng, box_lnb, box_Wf, box_bf,
        full_h, full_w, out, B, R);
}